// Round 1
// baseline (5886.917 us; speedup 1.0000x reference)
//
#include <hip/hip_runtime.h>
#include <hip/hip_bf16.h>
#include <math.h>

// Problem constants (fixed by the reference)
#define HEADS 32
#define DIM_HEAD 64
#define DM 2048          // HEADS * DIM_HEAD
#define BATCH 2
#define SEQ 1024
#define NROWS (BATCH * SEQ)      // 2048 rows of DM
#define NVEC (NROWS * HEADS)     // 65536 per-head vectors
#define N_GROUPS 22
#define N_LEVELS 8
#define EPS_NORM 1e-8f
#define EPS_RMS 1e-6f

// ---------------------------------------------------------------------------
// GEMM: C = A @ W.  A: N x K row-major, W: K x M row-major, C: N x M.
// 64x64 block tile, 256 threads, each thread 4x4 microtile, K-tile 16.
// ---------------------------------------------------------------------------
__global__ __launch_bounds__(256) void gemm_f32_kernel(
    const float* __restrict__ A, const float* __restrict__ W,
    float* __restrict__ C, int N, int K, int M) {
  __shared__ float As[16][64];  // As[k][m]
  __shared__ float Bs[16][64];  // Bs[k][n]
  const int t = threadIdx.x;
  const int row0 = blockIdx.y * 64;
  const int col0 = blockIdx.x * 64;
  const int tm = (t / 16) * 4;  // C row offset within tile
  const int tn = (t % 16) * 4;  // C col offset within tile
  float acc[4][4] = {{0.f}};

  for (int kt = 0; kt < K; kt += 16) {
    // A tile: 64 rows x 16 k. thread -> row t/4, k (t%4)*4 (+0..3), float4 load
    {
      const int r  = t >> 2;
      const int kk = (t & 3) << 2;
      const float4 a = *(const float4*)&A[(size_t)(row0 + r) * K + kt + kk];
      As[kk + 0][r] = a.x; As[kk + 1][r] = a.y;
      As[kk + 2][r] = a.z; As[kk + 3][r] = a.w;
    }
    // B tile: 16 k x 64 cols. thread -> k t/16, col (t%16)*4, float4 load
    {
      const int kk = t >> 4;
      const int c  = (t & 15) << 2;
      *(float4*)&Bs[kk][c] =
          *(const float4*)&W[(size_t)(kt + kk) * M + col0 + c];
    }
    __syncthreads();
#pragma unroll
    for (int k = 0; k < 16; ++k) {
      const float4 av = *(const float4*)&As[k][tm];
      const float4 bv = *(const float4*)&Bs[k][tn];
      const float a[4] = {av.x, av.y, av.z, av.w};
      const float b[4] = {bv.x, bv.y, bv.z, bv.w};
#pragma unroll
      for (int i = 0; i < 4; ++i)
#pragma unroll
        for (int j = 0; j < 4; ++j) acc[i][j] += a[i] * b[j];
    }
    __syncthreads();
  }
#pragma unroll
  for (int i = 0; i < 4; ++i) {
    float4 o = make_float4(acc[i][0], acc[i][1], acc[i][2], acc[i][3]);
    *(float4*)&C[(size_t)(row0 + tm + i) * M + col0 + tn] = o;
  }
}

// ---------------------------------------------------------------------------
// Wave (64-lane) reductions
// ---------------------------------------------------------------------------
__device__ __forceinline__ float wave_sum(float x) {
#pragma unroll
  for (int o = 32; o > 0; o >>= 1) x += __shfl_xor(x, o, 64);
  return x;
}
__device__ __forceinline__ float wave_max(float x) {
#pragma unroll
  for (int o = 32; o > 0; o >>= 1) x = fmaxf(x, __shfl_xor(x, o, 64));
  return x;
}

// ---------------------------------------------------------------------------
// RMSNorm over rows of DM elements, in place. One block per row.
// y = y * rsqrt(mean(y^2) + EPS_RMS) * w
// ---------------------------------------------------------------------------
__global__ __launch_bounds__(256) void rmsnorm_kernel(
    float* __restrict__ y, const float* __restrict__ w) {
  __shared__ float rbuf[4];
  const int row = blockIdx.x;
  float* p = y + (size_t)row * DM;
  const int t = threadIdx.x;
  const int wave = t >> 6, lane = t & 63;

  float ss = 0.f;
#pragma unroll
  for (int c = t; c < DM; c += 256) { float v = p[c]; ss += v * v; }
  ss = wave_sum(ss);
  if (lane == 0) rbuf[wave] = ss;
  __syncthreads();
  ss = rbuf[0] + rbuf[1] + rbuf[2] + rbuf[3];
  const float scale = rsqrtf(ss * (1.0f / DM) + EPS_RMS);
#pragma unroll
  for (int c = t; c < DM; c += 256) p[c] = p[c] * scale * w[c];
}

// ---------------------------------------------------------------------------
// RotorQuant compress+decompress roundtrip, in place.
// One thread per (b,s,h) vector of 64 contiguous floats.
// ---------------------------------------------------------------------------
__device__ __forceinline__ float qnearest(float v, const float* __restrict__ C) {
  // first-minimum scan == jnp.argmin tie-break
  float best = C[0];
  float bd = fabsf(v - C[0]);
#pragma unroll
  for (int i = 1; i < N_LEVELS; ++i) {
    float d = fabsf(v - C[i]);
    if (d < bd) { bd = d; best = C[i]; }
  }
  return best;
}

__global__ __launch_bounds__(256) void quant_kernel(
    float* __restrict__ kv, const float* __restrict__ M,
    const float* __restrict__ Mt, const float* __restrict__ C) {
  const int vec = blockIdx.x * blockDim.x + threadIdx.x;
  if (vec >= NVEC) return;
  float* p = kv + (size_t)vec * DIM_HEAD;

  float h[66];
  float ss = 0.f;
#pragma unroll
  for (int d = 0; d < DIM_HEAD; ++d) { h[d] = p[d]; ss += h[d] * h[d]; }
  float norm = fmaxf(sqrtf(ss), EPS_NORM);
  const float inv = 1.0f / norm;
#pragma unroll
  for (int d = 0; d < DIM_HEAD; ++d) h[d] *= inv;
  h[64] = 0.f; h[65] = 0.f;

#pragma unroll
  for (int g = 0; g < N_GROUPS; ++g) {
    const float* Mg  = M  + g * 9;
    const float* Mtg = Mt + g * 9;
    const float a0 = h[3 * g + 0], a1 = h[3 * g + 1], a2 = h[3 * g + 2];
    // rot[j] = sum_i a_i * M[i][j]
    const float r0 = a0 * Mg[0] + a1 * Mg[3] + a2 * Mg[6];
    const float r1 = a0 * Mg[1] + a1 * Mg[4] + a2 * Mg[7];
    const float r2 = a0 * Mg[2] + a1 * Mg[5] + a2 * Mg[8];
    const float d0 = qnearest(r0, C);
    const float d1 = qnearest(r1, C);
    const float d2 = qnearest(r2, C);
    // der[j] = sum_i d_i * Mt[i][j]
    h[3 * g + 0] = d0 * Mtg[0] + d1 * Mtg[3] + d2 * Mtg[6];
    h[3 * g + 1] = d0 * Mtg[1] + d1 * Mtg[4] + d2 * Mtg[7];
    h[3 * g + 2] = d0 * Mtg[2] + d1 * Mtg[5] + d2 * Mtg[8];
  }
#pragma unroll
  for (int d = 0; d < DIM_HEAD; ++d) p[d] = h[d] * norm;
}

// ---------------------------------------------------------------------------
// Attention: one block per (b, h, q-row). 256 threads = 4 waves.
// q,k,v in (B*S, DM) layout; head h occupies cols [64h, 64h+64).
// ---------------------------------------------------------------------------
__global__ __launch_bounds__(256) void attn_kernel(
    const float* __restrict__ q, const float* __restrict__ k,
    const float* __restrict__ v, float* __restrict__ o) {
  __shared__ float sq[64];
  __shared__ float sc[SEQ];
  __shared__ float rbuf[4];
  __shared__ float oacc[4][64];

  const int blk = blockIdx.x;
  const int qi = blk & (SEQ - 1);
  const int bh = blk >> 10;          // 0..63
  const int hh = bh & (HEADS - 1);
  const int b  = bh >> 5;

  const size_t headoff = (size_t)hh * DIM_HEAD;
  const float* qrow  = q + ((size_t)(b * SEQ + qi) * DM + headoff);
  const float* kbase = k + ((size_t)(b * SEQ) * DM + headoff);
  const float* vbase = v + ((size_t)(b * SEQ) * DM + headoff);

  const int t = threadIdx.x;
  const int wave = t >> 6, lane = t & 63;

  if (t < 64) sq[t] = qrow[t];
  __syncthreads();

  // scores: each wave computes rows wave, wave+4, ... via shuffle-reduced dot
  const float qd = sq[lane];
  for (int r = wave; r < SEQ; r += 4) {
    float p = qd * kbase[(size_t)r * DM + lane];
    p = wave_sum(p);
    if (lane == 0) sc[r] = p * 0.125f;  // 1/sqrt(64)
  }
  __syncthreads();

  // block max
  float m = -3.4e38f;
  for (int r = t; r < SEQ; r += 256) m = fmaxf(m, sc[r]);
  m = wave_max(m);
  if (lane == 0) rbuf[wave] = m;
  __syncthreads();
  m = fmaxf(fmaxf(rbuf[0], rbuf[1]), fmaxf(rbuf[2], rbuf[3]));
  __syncthreads();  // protect rbuf before reuse

  // exp + block sum
  float sum = 0.f;
  for (int r = t; r < SEQ; r += 256) {
    float e = expf(sc[r] - m);
    sc[r] = e;
    sum += e;
  }
  sum = wave_sum(sum);
  if (lane == 0) rbuf[wave] = sum;
  __syncthreads();
  const float invd = 1.0f / (rbuf[0] + rbuf[1] + rbuf[2] + rbuf[3]);

  // o[d] = sum_k p[k] * v[k][d]; thread = (chunk = t/64 over k, d = t%64)
  const int d = lane;
  const int chunk = wave;
  float acc = 0.f;
  const int r0 = chunk * (SEQ / 4);
  for (int r = r0; r < r0 + SEQ / 4; ++r)
    acc += sc[r] * vbase[(size_t)r * DM + d];
  oacc[chunk][d] = acc;
  __syncthreads();
  if (t < 64) {
    float res = (oacc[0][t] + oacc[1][t] + oacc[2][t] + oacc[3][t]) * invd;
    o[((size_t)(b * SEQ + qi) * DM + headoff) + t] = res;
  }
}

// ---------------------------------------------------------------------------
// Launch
// ---------------------------------------------------------------------------
extern "C" void kernel_launch(void* const* d_in, const int* in_sizes, int n_in,
                              void* d_out, int out_size, void* d_ws, size_t ws_size,
                              hipStream_t stream) {
  const float* x    = (const float*)d_in[0];
  const float* Wq   = (const float*)d_in[1];
  const float* Wk   = (const float*)d_in[2];
  const float* Wv   = (const float*)d_in[3];
  const float* Wo   = (const float*)d_in[4];
  const float* qn_w = (const float*)d_in[5];
  const float* kn_w = (const float*)d_in[6];
  const float* Mk   = (const float*)d_in[7];
  const float* Mtk  = (const float*)d_in[8];
  const float* Ck   = (const float*)d_in[9];
  const float* Mv   = (const float*)d_in[10];
  const float* Mtv  = (const float*)d_in[11];
  const float* Cv   = (const float*)d_in[12];
  float* out = (float*)d_out;

  const size_t mat_elems = (size_t)NROWS * DM;  // 4 Mi elements, 16 MiB
  float* qb = (float*)d_ws;
  float* kb = qb + mat_elems;
  float* vb = kb + mat_elems;
  float* ob = vb + mat_elems;

  dim3 ggrid(DM / 64, NROWS / 64);
  // q, k, v projections
  gemm_f32_kernel<<<ggrid, 256, 0, stream>>>(x, Wq, qb, NROWS, DM, DM);
  gemm_f32_kernel<<<ggrid, 256, 0, stream>>>(x, Wk, kb, NROWS, DM, DM);
  gemm_f32_kernel<<<ggrid, 256, 0, stream>>>(x, Wv, vb, NROWS, DM, DM);
  // rmsnorm q, k
  rmsnorm_kernel<<<NROWS, 256, 0, stream>>>(qb, qn_w);
  rmsnorm_kernel<<<NROWS, 256, 0, stream>>>(kb, kn_w);
  // rotor-quant roundtrip on k, v
  quant_kernel<<<NVEC / 256, 256, 0, stream>>>(kb, Mk, Mtk, Ck);
  quant_kernel<<<NVEC / 256, 256, 0, stream>>>(vb, Mv, Mtv, Cv);
  // attention
  attn_kernel<<<BATCH * HEADS * SEQ, 256, 0, stream>>>(qb, kb, vb, ob);
  // output projection
  gemm_f32_kernel<<<ggrid, 256, 0, stream>>>(ob, Wo, out, NROWS, DM, DM);
}

// Round 2
// 1370.698 us; speedup vs baseline: 4.2948x; 4.2948x over previous
//
#include <hip/hip_runtime.h>
#include <hip/hip_bf16.h>
#include <math.h>

// Problem constants (fixed by the reference)
#define HEADS 32
#define DIM_HEAD 64
#define DM 2048          // HEADS * DIM_HEAD
#define BATCH 2
#define SEQ 1024
#define NROWS (BATCH * SEQ)      // 2048 rows of DM
#define NVEC (NROWS * HEADS)     // 65536 per-head vectors
#define N_GROUPS 22
#define N_LEVELS 8
#define EPS_NORM 1e-8f
#define EPS_RMS 1e-6f

// ---------------------------------------------------------------------------
// GEMM: C = A @ W.  A: N x K row-major, W: K x M row-major, C: N x M.
// 64x64 block tile, 256 threads, each thread 4x4 microtile, K-tile 16.
// ---------------------------------------------------------------------------
__global__ __launch_bounds__(256) void gemm_f32_kernel(
    const float* __restrict__ A, const float* __restrict__ W,
    float* __restrict__ C, int N, int K, int M) {
  __shared__ float As[16][64];  // As[k][m]
  __shared__ float Bs[16][64];  // Bs[k][n]
  const int t = threadIdx.x;
  const int row0 = blockIdx.y * 64;
  const int col0 = blockIdx.x * 64;
  const int tm = (t / 16) * 4;  // C row offset within tile
  const int tn = (t % 16) * 4;  // C col offset within tile
  float acc[4][4] = {{0.f}};

  for (int kt = 0; kt < K; kt += 16) {
    {
      const int r  = t >> 2;
      const int kk = (t & 3) << 2;
      const float4 a = *(const float4*)&A[(size_t)(row0 + r) * K + kt + kk];
      As[kk + 0][r] = a.x; As[kk + 1][r] = a.y;
      As[kk + 2][r] = a.z; As[kk + 3][r] = a.w;
    }
    {
      const int kk = t >> 4;
      const int c  = (t & 15) << 2;
      *(float4*)&Bs[kk][c] =
          *(const float4*)&W[(size_t)(kt + kk) * M + col0 + c];
    }
    __syncthreads();
#pragma unroll
    for (int k = 0; k < 16; ++k) {
      const float4 av = *(const float4*)&As[k][tm];
      const float4 bv = *(const float4*)&Bs[k][tn];
      const float a[4] = {av.x, av.y, av.z, av.w};
      const float b[4] = {bv.x, bv.y, bv.z, bv.w};
#pragma unroll
      for (int i = 0; i < 4; ++i)
#pragma unroll
        for (int j = 0; j < 4; ++j) acc[i][j] += a[i] * b[j];
    }
    __syncthreads();
  }
#pragma unroll
  for (int i = 0; i < 4; ++i) {
    float4 o = make_float4(acc[i][0], acc[i][1], acc[i][2], acc[i][3]);
    *(float4*)&C[(size_t)(row0 + tm + i) * M + col0 + tn] = o;
  }
}

// ---------------------------------------------------------------------------
// Wave (64-lane) reductions
// ---------------------------------------------------------------------------
__device__ __forceinline__ float wave_sum(float x) {
#pragma unroll
  for (int o = 32; o > 0; o >>= 1) x += __shfl_xor(x, o, 64);
  return x;
}

// ---------------------------------------------------------------------------
// RMSNorm over rows of DM elements, in place. One block per row.
// ---------------------------------------------------------------------------
__global__ __launch_bounds__(256) void rmsnorm_kernel(
    float* __restrict__ y, const float* __restrict__ w) {
  __shared__ float rbuf[4];
  const int row = blockIdx.x;
  float* p = y + (size_t)row * DM;
  const int t = threadIdx.x;
  const int wave = t >> 6, lane = t & 63;

  float ss = 0.f;
#pragma unroll
  for (int c = t; c < DM; c += 256) { float v = p[c]; ss += v * v; }
  ss = wave_sum(ss);
  if (lane == 0) rbuf[wave] = ss;
  __syncthreads();
  ss = rbuf[0] + rbuf[1] + rbuf[2] + rbuf[3];
  const float scale = rsqrtf(ss * (1.0f / DM) + EPS_RMS);
#pragma unroll
  for (int c = t; c < DM; c += 256) p[c] = p[c] * scale * w[c];
}

// ---------------------------------------------------------------------------
// RotorQuant compress+decompress roundtrip, in place.
// One thread per (b,s,h) vector of 64 contiguous floats.
// ---------------------------------------------------------------------------
__device__ __forceinline__ float qnearest(float v, const float* __restrict__ C) {
  float best = C[0];
  float bd = fabsf(v - C[0]);
#pragma unroll
  for (int i = 1; i < N_LEVELS; ++i) {
    float d = fabsf(v - C[i]);
    if (d < bd) { bd = d; best = C[i]; }
  }
  return best;
}

__global__ __launch_bounds__(256) void quant_kernel(
    float* __restrict__ kv, const float* __restrict__ M,
    const float* __restrict__ Mt, const float* __restrict__ C) {
  const int vec = blockIdx.x * blockDim.x + threadIdx.x;
  if (vec >= NVEC) return;
  float* p = kv + (size_t)vec * DIM_HEAD;

  float h[66];
  float ss = 0.f;
#pragma unroll
  for (int d = 0; d < DIM_HEAD; ++d) { h[d] = p[d]; ss += h[d] * h[d]; }
  float norm = fmaxf(sqrtf(ss), EPS_NORM);
  const float inv = 1.0f / norm;
#pragma unroll
  for (int d = 0; d < DIM_HEAD; ++d) h[d] *= inv;
  h[64] = 0.f; h[65] = 0.f;

#pragma unroll
  for (int g = 0; g < N_GROUPS; ++g) {
    const float* Mg  = M  + g * 9;
    const float* Mtg = Mt + g * 9;
    const float a0 = h[3 * g + 0], a1 = h[3 * g + 1], a2 = h[3 * g + 2];
    const float r0 = a0 * Mg[0] + a1 * Mg[3] + a2 * Mg[6];
    const float r1 = a0 * Mg[1] + a1 * Mg[4] + a2 * Mg[7];
    const float r2 = a0 * Mg[2] + a1 * Mg[5] + a2 * Mg[8];
    const float d0 = qnearest(r0, C);
    const float d1 = qnearest(r1, C);
    const float d2 = qnearest(r2, C);
    h[3 * g + 0] = d0 * Mtg[0] + d1 * Mtg[3] + d2 * Mtg[6];
    h[3 * g + 1] = d0 * Mtg[1] + d1 * Mtg[4] + d2 * Mtg[7];
    h[3 * g + 2] = d0 * Mtg[2] + d1 * Mtg[5] + d2 * Mtg[8];
  }
#pragma unroll
  for (int d = 0; d < DIM_HEAD; ++d) p[d] = h[d] * norm;
}

// ---------------------------------------------------------------------------
// Flash attention, fp32. One block per (b, h, 64-row q-tile).
// 256 threads; thread (qg = t>>4, kg = t&15) owns a 4x4 microtile.
// Online softmax; K/V tiles staged in LDS; S and PV as outer-product GEMMs.
// ---------------------------------------------------------------------------
__global__ __launch_bounds__(256) void flash_attn_kernel(
    const float* __restrict__ q, const float* __restrict__ k,
    const float* __restrict__ v, float* __restrict__ o) {
  __shared__ float Qt[64][68];  // [d][q], pre-scaled by 1/8
  __shared__ float Kt[64][68];  // [d][k]
  __shared__ float Vs[64][68];  // [k][d]
  __shared__ float Pt[64][68];  // [k][q]

  const int blk = blockIdx.x;
  const int qt = blk & 15;
  const int bh = blk >> 4;
  const int h  = bh & (HEADS - 1);
  const int b  = bh >> 5;
  const int q0 = qt * 64;

  const size_t headoff = (size_t)h * DIM_HEAD;
  const float* qbase = q + ((size_t)(b * SEQ + q0) * DM + headoff);
  const float* kbase = k + ((size_t)(b * SEQ) * DM + headoff);
  const float* vbase = v + ((size_t)(b * SEQ) * DM + headoff);
  float* obase       = o + ((size_t)(b * SEQ + q0) * DM + headoff);

  const int t = threadIdx.x;
  const int qg = t >> 4;   // 0..15 -> q rows 4qg..4qg+3
  const int kg = t & 15;   // 0..15 -> k cols (and d cols) 4kg..4kg+3
  const int lr = t >> 2;   // load row 0..63
  const int ls = t & 3;    // load segment 0..3 (16 cols each)

  // Load Q tile transposed into LDS, folding the 1/sqrt(64) score scale.
  {
    const float* src = qbase + (size_t)lr * DM + ls * 16;
#pragma unroll
    for (int c4 = 0; c4 < 4; ++c4) {
      float4 a = *(const float4*)(src + c4 * 4);
      int c = ls * 16 + c4 * 4;
      Qt[c + 0][lr] = a.x * 0.125f;
      Qt[c + 1][lr] = a.y * 0.125f;
      Qt[c + 2][lr] = a.z * 0.125f;
      Qt[c + 3][lr] = a.w * 0.125f;
    }
  }

  float acc[4][4] = {{0.f}};
  float m_prev[4] = {-INFINITY, -INFINITY, -INFINITY, -INFINITY};
  float l[4] = {0.f, 0.f, 0.f, 0.f};

  for (int kt = 0; kt < SEQ; kt += 64) {
    __syncthreads();  // previous PV reads done before overwriting K/V tiles
    // K tile transposed
    {
      const float* src = kbase + (size_t)(kt + lr) * DM + ls * 16;
#pragma unroll
      for (int c4 = 0; c4 < 4; ++c4) {
        float4 a = *(const float4*)(src + c4 * 4);
        int c = ls * 16 + c4 * 4;
        Kt[c + 0][lr] = a.x; Kt[c + 1][lr] = a.y;
        Kt[c + 2][lr] = a.z; Kt[c + 3][lr] = a.w;
      }
    }
    // V tile natural layout
    {
      const float* src = vbase + (size_t)(kt + lr) * DM + ls * 16;
#pragma unroll
      for (int c4 = 0; c4 < 4; ++c4) {
        *(float4*)&Vs[lr][ls * 16 + c4 * 4] = *(const float4*)(src + c4 * 4);
      }
    }
    __syncthreads();

    // S = (Q/8) @ K^T, 4x4 microtile over d
    float s[4][4] = {{0.f}};
#pragma unroll 8
    for (int d = 0; d < 64; ++d) {
      const float4 a = *(const float4*)&Qt[d][qg * 4];
      const float4 bb = *(const float4*)&Kt[d][kg * 4];
      s[0][0] += a.x * bb.x; s[0][1] += a.x * bb.y; s[0][2] += a.x * bb.z; s[0][3] += a.x * bb.w;
      s[1][0] += a.y * bb.x; s[1][1] += a.y * bb.y; s[1][2] += a.y * bb.z; s[1][3] += a.y * bb.w;
      s[2][0] += a.z * bb.x; s[2][1] += a.z * bb.y; s[2][2] += a.z * bb.z; s[2][3] += a.z * bb.w;
      s[3][0] += a.w * bb.x; s[3][1] += a.w * bb.y; s[3][2] += a.w * bb.z; s[3][3] += a.w * bb.w;
    }

    // Online softmax update per q row (16 lanes share a row: lane bits 0..3)
#pragma unroll
    for (int i = 0; i < 4; ++i) {
      float tm = fmaxf(fmaxf(s[i][0], s[i][1]), fmaxf(s[i][2], s[i][3]));
#pragma unroll
      for (int off = 1; off < 16; off <<= 1) tm = fmaxf(tm, __shfl_xor(tm, off, 64));
      const float mn = fmaxf(m_prev[i], tm);
      const float al = __expf(m_prev[i] - mn);
      float rs = 0.f;
#pragma unroll
      for (int j = 0; j < 4; ++j) { s[i][j] = __expf(s[i][j] - mn); rs += s[i][j]; }
#pragma unroll
      for (int off = 1; off < 16; off <<= 1) rs += __shfl_xor(rs, off, 64);
      l[i] = l[i] * al + rs;
      m_prev[i] = mn;
#pragma unroll
      for (int j = 0; j < 4; ++j) acc[i][j] *= al;
    }

    // Write P transposed for the PV outer-product
#pragma unroll
    for (int j = 0; j < 4; ++j)
#pragma unroll
      for (int i = 0; i < 4; ++i)
        Pt[kg * 4 + j][qg * 4 + i] = s[i][j];
    __syncthreads();

    // O += P @ V
#pragma unroll 8
    for (int kk = 0; kk < 64; ++kk) {
      const float4 a = *(const float4*)&Pt[kk][qg * 4];
      const float4 bb = *(const float4*)&Vs[kk][kg * 4];
      acc[0][0] += a.x * bb.x; acc[0][1] += a.x * bb.y; acc[0][2] += a.x * bb.z; acc[0][3] += a.x * bb.w;
      acc[1][0] += a.y * bb.x; acc[1][1] += a.y * bb.y; acc[1][2] += a.y * bb.z; acc[1][3] += a.y * bb.w;
      acc[2][0] += a.z * bb.x; acc[2][1] += a.z * bb.y; acc[2][2] += a.z * bb.z; acc[2][3] += a.z * bb.w;
      acc[3][0] += a.w * bb.x; acc[3][1] += a.w * bb.y; acc[3][2] += a.w * bb.z; acc[3][3] += a.w * bb.w;
    }
  }

  // Epilogue: divide by softmax denominator, write out
#pragma unroll
  for (int i = 0; i < 4; ++i) {
    const float inv = 1.0f / l[i];
    float4 ov = make_float4(acc[i][0] * inv, acc[i][1] * inv,
                            acc[i][2] * inv, acc[i][3] * inv);
    *(float4*)(obase + (size_t)(qg * 4 + i) * DM + kg * 4) = ov;
  }
}

// ---------------------------------------------------------------------------
// Launch
// ---------------------------------------------------------------------------
extern "C" void kernel_launch(void* const* d_in, const int* in_sizes, int n_in,
                              void* d_out, int out_size, void* d_ws, size_t ws_size,
                              hipStream_t stream) {
  const float* x    = (const float*)d_in[0];
  const float* Wq   = (const float*)d_in[1];
  const float* Wk   = (const float*)d_in[2];
  const float* Wv   = (const float*)d_in[3];
  const float* Wo   = (const float*)d_in[4];
  const float* qn_w = (const float*)d_in[5];
  const float* kn_w = (const float*)d_in[6];
  const float* Mk   = (const float*)d_in[7];
  const float* Mtk  = (const float*)d_in[8];
  const float* Ck   = (const float*)d_in[9];
  const float* Mv   = (const float*)d_in[10];
  const float* Mtv  = (const float*)d_in[11];
  const float* Cv   = (const float*)d_in[12];
  float* out = (float*)d_out;

  const size_t mat_elems = (size_t)NROWS * DM;  // 4 Mi elements, 16 MiB
  float* qb = (float*)d_ws;
  float* kb = qb + mat_elems;
  float* vb = kb + mat_elems;
  float* ob = vb + mat_elems;

  dim3 ggrid(DM / 64, NROWS / 64);
  gemm_f32_kernel<<<ggrid, 256, 0, stream>>>(x, Wq, qb, NROWS, DM, DM);
  gemm_f32_kernel<<<ggrid, 256, 0, stream>>>(x, Wk, kb, NROWS, DM, DM);
  gemm_f32_kernel<<<ggrid, 256, 0, stream>>>(x, Wv, vb, NROWS, DM, DM);
  rmsnorm_kernel<<<NROWS, 256, 0, stream>>>(qb, qn_w);
  rmsnorm_kernel<<<NROWS, 256, 0, stream>>>(kb, kn_w);
  quant_kernel<<<NVEC / 256, 256, 0, stream>>>(kb, Mk, Mtk, Ck);
  quant_kernel<<<NVEC / 256, 256, 0, stream>>>(vb, Mv, Mtv, Cv);
  flash_attn_kernel<<<BATCH * HEADS * SEQ / 64, 256, 0, stream>>>(qb, kb, vb, ob);
  gemm_f32_kernel<<<ggrid, 256, 0, stream>>>(ob, Wo, out, NROWS, DM, DM);
}

// Round 3
// 717.835 us; speedup vs baseline: 8.2009x; 1.9095x over previous
//
#include <hip/hip_runtime.h>
#include <hip/hip_bf16.h>
#include <math.h>

// Problem constants (fixed by the reference)
#define HEADS 32
#define DIM_HEAD 64
#define DM 2048          // HEADS * DIM_HEAD
#define BATCH 2
#define SEQ 1024
#define NROWS (BATCH * SEQ)      // 2048 rows of DM
#define NVEC (NROWS * HEADS)     // 65536 per-head vectors
#define N_GROUPS 22
#define N_LEVELS 8
#define EPS_NORM 1e-8f
#define EPS_RMS 1e-6f

typedef float f32x4 __attribute__((ext_vector_type(4)));
typedef __bf16 bf16x8 __attribute__((ext_vector_type(8)));
typedef unsigned short u16x8 __attribute__((ext_vector_type(8)));

__device__ __forceinline__ unsigned short f2bf(float x) {
  union { float f; unsigned u; } v; v.f = x;
  unsigned r = v.u + 0x7fffu + ((v.u >> 16) & 1u);  // RTN-even
  return (unsigned short)(r >> 16);
}
__device__ __forceinline__ float bf2f(unsigned short h) {
  union { unsigned u; float f; } v; v.u = ((unsigned)h) << 16;
  return v.f;
}

// ---------------------------------------------------------------------------
// fp32 -> bf16 hi/lo split (lo optional), 8 elements/thread
// ---------------------------------------------------------------------------
__global__ __launch_bounds__(256) void split_convert_kernel(
    const float* __restrict__ X, unsigned short* __restrict__ hi,
    unsigned short* __restrict__ lo, int n8) {
  const int i = blockIdx.x * 256 + threadIdx.x;
  if (i >= n8) return;
  const float4 a = ((const float4*)X)[2 * i];
  const float4 b = ((const float4*)X)[2 * i + 1];
  const float v[8] = {a.x, a.y, a.z, a.w, b.x, b.y, b.z, b.w};
  u16x8 h, l;
#pragma unroll
  for (int j = 0; j < 8; ++j) {
    const unsigned short hh = f2bf(v[j]);
    h[j] = hh;
    l[j] = f2bf(v[j] - bf2f(hh));
  }
  ((u16x8*)hi)[i] = h;
  if (lo) ((u16x8*)lo)[i] = l;
}

// ---------------------------------------------------------------------------
// W [K][M] fp32 -> Th/Tl [M][K] bf16 hi/lo (transpose + split; lo optional)
// ---------------------------------------------------------------------------
__global__ __launch_bounds__(256) void transpose_split_kernel(
    const float* __restrict__ W, unsigned short* __restrict__ Th,
    unsigned short* __restrict__ Tl, int K, int M) {
  __shared__ float S[64][65];
  const int t = threadIdx.x;
  const int tk = blockIdx.y * 64, tm = blockIdx.x * 64;
  {
    const int r = t >> 2, cs = (t & 3) * 16;
    const float* src = W + (size_t)(tk + r) * M + tm + cs;
#pragma unroll
    for (int j = 0; j < 16; j += 4) {
      float4 v = *(const float4*)(src + j);
      S[r][cs + j] = v.x; S[r][cs + j + 1] = v.y;
      S[r][cs + j + 2] = v.z; S[r][cs + j + 3] = v.w;
    }
  }
  __syncthreads();
  const int m = t >> 2, ks = (t & 3) * 16;
  u16x8 h0, h1, l0, l1;
#pragma unroll
  for (int j = 0; j < 8; ++j) {
    const float v = S[ks + j][m];
    const unsigned short hh = f2bf(v);
    h0[j] = hh; l0[j] = f2bf(v - bf2f(hh));
  }
#pragma unroll
  for (int j = 0; j < 8; ++j) {
    const float v = S[ks + 8 + j][m];
    const unsigned short hh = f2bf(v);
    h1[j] = hh; l1[j] = f2bf(v - bf2f(hh));
  }
  const size_t o = (size_t)(tm + m) * K + tk + ks;
  *(u16x8*)&Th[o] = h0; *(u16x8*)&Th[o + 8] = h1;
  if (Tl) { *(u16x8*)&Tl[o] = l0; *(u16x8*)&Tl[o + 8] = l1; }
}

// ---------------------------------------------------------------------------
// MFMA GEMM (m97 recipe): C[N,M] = A[N,K] @ Bt[M,K]^T, all bf16 inputs,
// fp32 accumulate. 128x128 tile, BK=32, 256 threads (4 waves, 64x64 each,
// 4x4 grid of 16x16x32 MFMA). global_load_lds width-16 staging with an
// XOR-swizzle on 16B chunks: phys_chunk = chunk ^ ((row>>1)&3), which makes
// fragment ds_read_b128 exactly 2-way bank-aliased (free on CDNA4).
// SPLIT: A/B given as hi+lo bf16 pairs; 3 MFMAs (hh + hl + lh) ~= fp32.
// ---------------------------------------------------------------------------
__device__ __forceinline__ void stage16(const unsigned short* g, unsigned short* lds) {
  __builtin_amdgcn_global_load_lds(
      (const __attribute__((address_space(1))) unsigned int*)g,
      (__attribute__((address_space(3))) unsigned int*)lds, 16, 0, 0);
}

template <bool SPLIT>
__global__ __launch_bounds__(256) void gemm_mfma_kernel(
    const unsigned short* __restrict__ Ahi, const unsigned short* __restrict__ Alo,
    const unsigned short* __restrict__ Bhi, const unsigned short* __restrict__ Blo,
    float* __restrict__ C, int N, int K, int M) {
  __shared__ unsigned short lAhi[128 * 32];
  __shared__ unsigned short lBhi[128 * 32];
  __shared__ unsigned short lAlo[SPLIT ? 128 * 32 : 8];
  __shared__ unsigned short lBlo[SPLIT ? 128 * 32 : 8];

  const int t = threadIdx.x;
  const int lane = t & 63, wave = t >> 6;
  const int wr = wave >> 1, wc = wave & 1;
  const int gm0 = blockIdx.y * 128, gn0 = blockIdx.x * 128;
  const int lrsub = lane >> 2;   // 0..15: row within staging region
  const int lcsub = lane & 3;    // 0..3:  physical 16B chunk within row

  f32x4 acc[4][4] = {};

  for (int kt = 0; kt < K; kt += 32) {
    __syncthreads();  // previous iteration's fragment reads done
#pragma unroll
    for (int rg = wave; rg < 8; rg += 4) {
      const int lrow = rg * 16 + lrsub;
      const int c = lcsub ^ ((lrow >> 1) & 3);  // logical chunk this lane fetches
      const size_t goffA = (size_t)(gm0 + lrow) * K + kt + c * 8;
      const size_t goffB = (size_t)(gn0 + lrow) * K + kt + c * 8;
      stage16(Ahi + goffA, lAhi + rg * 512);
      stage16(Bhi + goffB, lBhi + rg * 512);
      if (SPLIT) {
        stage16(Alo + goffA, lAlo + rg * 512);
        stage16(Blo + goffB, lBlo + rg * 512);
      }
    }
    __syncthreads();  // staging complete (vmcnt(0) drained by barrier)

    bf16x8 ah[4], bh[4], al[4], bl[4];
#pragma unroll
    for (int i = 0; i < 4; ++i) {
      const int mrow = wr * 64 + i * 16 + (lane & 15);
      const int offa = mrow * 32 + (((lane >> 4) ^ ((mrow >> 1) & 3)) << 3);
      ah[i] = __builtin_bit_cast(bf16x8, *(const u16x8*)&lAhi[offa]);
      if (SPLIT) al[i] = __builtin_bit_cast(bf16x8, *(const u16x8*)&lAlo[offa]);
      const int nrow = wc * 64 + i * 16 + (lane & 15);
      const int offb = nrow * 32 + (((lane >> 4) ^ ((nrow >> 1) & 3)) << 3);
      bh[i] = __builtin_bit_cast(bf16x8, *(const u16x8*)&lBhi[offb]);
      if (SPLIT) bl[i] = __builtin_bit_cast(bf16x8, *(const u16x8*)&lBlo[offb]);
    }
#pragma unroll
    for (int i = 0; i < 4; ++i)
#pragma unroll
      for (int j = 0; j < 4; ++j) {
        acc[i][j] = __builtin_amdgcn_mfma_f32_16x16x32_bf16(ah[i], bh[j], acc[i][j], 0, 0, 0);
        if (SPLIT) {
          acc[i][j] = __builtin_amdgcn_mfma_f32_16x16x32_bf16(ah[i], bl[j], acc[i][j], 0, 0, 0);
          acc[i][j] = __builtin_amdgcn_mfma_f32_16x16x32_bf16(al[i], bh[j], acc[i][j], 0, 0, 0);
        }
      }
  }

  // C/D layout (m89-verified): col = lane&15, row = (lane>>4)*4 + reg
#pragma unroll
  for (int i = 0; i < 4; ++i) {
    const int row = gm0 + wr * 64 + i * 16 + ((lane >> 4) << 2);
#pragma unroll
    for (int j = 0; j < 4; ++j) {
      const int col = gn0 + wc * 64 + j * 16 + (lane & 15);
#pragma unroll
      for (int r = 0; r < 4; ++r)
        C[(size_t)(row + r) * M + col] = acc[i][j][r];
    }
  }
}

// ---------------------------------------------------------------------------
// Wave (64-lane) reductions
// ---------------------------------------------------------------------------
__device__ __forceinline__ float wave_sum(float x) {
#pragma unroll
  for (int o = 32; o > 0; o >>= 1) x += __shfl_xor(x, o, 64);
  return x;
}

// ---------------------------------------------------------------------------
// RMSNorm over rows of DM elements, in place. One block per row.
// ---------------------------------------------------------------------------
__global__ __launch_bounds__(256) void rmsnorm_kernel(
    float* __restrict__ y, const float* __restrict__ w) {
  __shared__ float rbuf[4];
  const int row = blockIdx.x;
  float* p = y + (size_t)row * DM;
  const int t = threadIdx.x;
  const int wave = t >> 6, lane = t & 63;

  float ss = 0.f;
#pragma unroll
  for (int c = t; c < DM; c += 256) { float v = p[c]; ss += v * v; }
  ss = wave_sum(ss);
  if (lane == 0) rbuf[wave] = ss;
  __syncthreads();
  ss = rbuf[0] + rbuf[1] + rbuf[2] + rbuf[3];
  const float scale = rsqrtf(ss * (1.0f / DM) + EPS_RMS);
#pragma unroll
  for (int c = t; c < DM; c += 256) p[c] = p[c] * scale * w[c];
}

// ---------------------------------------------------------------------------
// RotorQuant compress+decompress roundtrip, in place.
// ---------------------------------------------------------------------------
__device__ __forceinline__ float qnearest(float v, const float* __restrict__ C) {
  float best = C[0];
  float bd = fabsf(v - C[0]);
#pragma unroll
  for (int i = 1; i < N_LEVELS; ++i) {
    float d = fabsf(v - C[i]);
    if (d < bd) { bd = d; best = C[i]; }
  }
  return best;
}

__global__ __launch_bounds__(256) void quant_kernel(
    float* __restrict__ kv, const float* __restrict__ M,
    const float* __restrict__ Mt, const float* __restrict__ C) {
  const int vec = blockIdx.x * blockDim.x + threadIdx.x;
  if (vec >= NVEC) return;
  float* p = kv + (size_t)vec * DIM_HEAD;

  float h[66];
  float ss = 0.f;
#pragma unroll
  for (int d = 0; d < DIM_HEAD; ++d) { h[d] = p[d]; ss += h[d] * h[d]; }
  float norm = fmaxf(sqrtf(ss), EPS_NORM);
  const float inv = 1.0f / norm;
#pragma unroll
  for (int d = 0; d < DIM_HEAD; ++d) h[d] *= inv;
  h[64] = 0.f; h[65] = 0.f;

#pragma unroll
  for (int g = 0; g < N_GROUPS; ++g) {
    const float* Mg  = M  + g * 9;
    const float* Mtg = Mt + g * 9;
    const float a0 = h[3 * g + 0], a1 = h[3 * g + 1], a2 = h[3 * g + 2];
    const float r0 = a0 * Mg[0] + a1 * Mg[3] + a2 * Mg[6];
    const float r1 = a0 * Mg[1] + a1 * Mg[4] + a2 * Mg[7];
    const float r2 = a0 * Mg[2] + a1 * Mg[5] + a2 * Mg[8];
    const float d0 = qnearest(r0, C);
    const float d1 = qnearest(r1, C);
    const float d2 = qnearest(r2, C);
    h[3 * g + 0] = d0 * Mtg[0] + d1 * Mtg[3] + d2 * Mtg[6];
    h[3 * g + 1] = d0 * Mtg[1] + d1 * Mtg[4] + d2 * Mtg[7];
    h[3 * g + 2] = d0 * Mtg[2] + d1 * Mtg[5] + d2 * Mtg[8];
  }
#pragma unroll
  for (int d = 0; d < DIM_HEAD; ++d) p[d] = h[d] * norm;
}

// ---------------------------------------------------------------------------
// Flash attention, fp32 (unchanged from round 2).
// ---------------------------------------------------------------------------
__global__ __launch_bounds__(256) void flash_attn_kernel(
    const float* __restrict__ q, const float* __restrict__ k,
    const float* __restrict__ v, float* __restrict__ o) {
  __shared__ float Qt[64][68];
  __shared__ float Kt[64][68];
  __shared__ float Vs[64][68];
  __shared__ float Pt[64][68];

  const int blk = blockIdx.x;
  const int qt = blk & 15;
  const int bh = blk >> 4;
  const int h  = bh & (HEADS - 1);
  const int b  = bh >> 5;
  const int q0 = qt * 64;

  const size_t headoff = (size_t)h * DIM_HEAD;
  const float* qbase = q + ((size_t)(b * SEQ + q0) * DM + headoff);
  const float* kbase = k + ((size_t)(b * SEQ) * DM + headoff);
  const float* vbase = v + ((size_t)(b * SEQ) * DM + headoff);
  float* obase       = o + ((size_t)(b * SEQ + q0) * DM + headoff);

  const int t = threadIdx.x;
  const int qg = t >> 4;
  const int kg = t & 15;
  const int lr = t >> 2;
  const int ls = t & 3;

  {
    const float* src = qbase + (size_t)lr * DM + ls * 16;
#pragma unroll
    for (int c4 = 0; c4 < 4; ++c4) {
      float4 a = *(const float4*)(src + c4 * 4);
      int c = ls * 16 + c4 * 4;
      Qt[c + 0][lr] = a.x * 0.125f;
      Qt[c + 1][lr] = a.y * 0.125f;
      Qt[c + 2][lr] = a.z * 0.125f;
      Qt[c + 3][lr] = a.w * 0.125f;
    }
  }

  float acc[4][4] = {{0.f}};
  float m_prev[4] = {-INFINITY, -INFINITY, -INFINITY, -INFINITY};
  float l[4] = {0.f, 0.f, 0.f, 0.f};

  for (int kt = 0; kt < SEQ; kt += 64) {
    __syncthreads();
    {
      const float* src = kbase + (size_t)(kt + lr) * DM + ls * 16;
#pragma unroll
      for (int c4 = 0; c4 < 4; ++c4) {
        float4 a = *(const float4*)(src + c4 * 4);
        int c = ls * 16 + c4 * 4;
        Kt[c + 0][lr] = a.x; Kt[c + 1][lr] = a.y;
        Kt[c + 2][lr] = a.z; Kt[c + 3][lr] = a.w;
      }
    }
    {
      const float* src = vbase + (size_t)(kt + lr) * DM + ls * 16;
#pragma unroll
      for (int c4 = 0; c4 < 4; ++c4) {
        *(float4*)&Vs[lr][ls * 16 + c4 * 4] = *(const float4*)(src + c4 * 4);
      }
    }
    __syncthreads();

    float s[4][4] = {{0.f}};
#pragma unroll 8
    for (int d = 0; d < 64; ++d) {
      const float4 a = *(const float4*)&Qt[d][qg * 4];
      const float4 bb = *(const float4*)&Kt[d][kg * 4];
      s[0][0] += a.x * bb.x; s[0][1] += a.x * bb.y; s[0][2] += a.x * bb.z; s[0][3] += a.x * bb.w;
      s[1][0] += a.y * bb.x; s[1][1] += a.y * bb.y; s[1][2] += a.y * bb.z; s[1][3] += a.y * bb.w;
      s[2][0] += a.z * bb.x; s[2][1] += a.z * bb.y; s[2][2] += a.z * bb.z; s[2][3] += a.z * bb.w;
      s[3][0] += a.w * bb.x; s[3][1] += a.w * bb.y; s[3][2] += a.w * bb.z; s[3][3] += a.w * bb.w;
    }

#pragma unroll
    for (int i = 0; i < 4; ++i) {
      float tm = fmaxf(fmaxf(s[i][0], s[i][1]), fmaxf(s[i][2], s[i][3]));
#pragma unroll
      for (int off = 1; off < 16; off <<= 1) tm = fmaxf(tm, __shfl_xor(tm, off, 64));
      const float mn = fmaxf(m_prev[i], tm);
      const float al = __expf(m_prev[i] - mn);
      float rs = 0.f;
#pragma unroll
      for (int j = 0; j < 4; ++j) { s[i][j] = __expf(s[i][j] - mn); rs += s[i][j]; }
#pragma unroll
      for (int off = 1; off < 16; off <<= 1) rs += __shfl_xor(rs, off, 64);
      l[i] = l[i] * al + rs;
      m_prev[i] = mn;
#pragma unroll
      for (int j = 0; j < 4; ++j) acc[i][j] *= al;
    }

#pragma unroll
    for (int j = 0; j < 4; ++j)
#pragma unroll
      for (int i = 0; i < 4; ++i)
        Pt[kg * 4 + j][qg * 4 + i] = s[i][j];
    __syncthreads();

#pragma unroll 8
    for (int kk = 0; kk < 64; ++kk) {
      const float4 a = *(const float4*)&Pt[kk][qg * 4];
      const float4 bb = *(const float4*)&Vs[kk][kg * 4];
      acc[0][0] += a.x * bb.x; acc[0][1] += a.x * bb.y; acc[0][2] += a.x * bb.z; acc[0][3] += a.x * bb.w;
      acc[1][0] += a.y * bb.x; acc[1][1] += a.y * bb.y; acc[1][2] += a.y * bb.z; acc[1][3] += a.y * bb.w;
      acc[2][0] += a.z * bb.x; acc[2][1] += a.z * bb.y; acc[2][2] += a.z * bb.z; acc[2][3] += a.z * bb.w;
      acc[3][0] += a.w * bb.x; acc[3][1] += a.w * bb.y; acc[3][2] += a.w * bb.z; acc[3][3] += a.w * bb.w;
    }
  }

#pragma unroll
  for (int i = 0; i < 4; ++i) {
    const float inv = 1.0f / l[i];
    float4 ov = make_float4(acc[i][0] * inv, acc[i][1] * inv,
                            acc[i][2] * inv, acc[i][3] * inv);
    *(float4*)(obase + (size_t)(qg * 4 + i) * DM + kg * 4) = ov;
  }
}

// ---------------------------------------------------------------------------
// Launch
// ---------------------------------------------------------------------------
extern "C" void kernel_launch(void* const* d_in, const int* in_sizes, int n_in,
                              void* d_out, int out_size, void* d_ws, size_t ws_size,
                              hipStream_t stream) {
  const float* x    = (const float*)d_in[0];
  const float* Wq   = (const float*)d_in[1];
  const float* Wk   = (const float*)d_in[2];
  const float* Wv   = (const float*)d_in[3];
  const float* Wo   = (const float*)d_in[4];
  const float* qn_w = (const float*)d_in[5];
  const float* kn_w = (const float*)d_in[6];
  const float* Mk   = (const float*)d_in[7];
  const float* Mtk  = (const float*)d_in[8];
  const float* Ck   = (const float*)d_in[9];
  const float* Mv   = (const float*)d_in[10];
  const float* Mtv  = (const float*)d_in[11];
  const float* Cv   = (const float*)d_in[12];
  float* out = (float*)d_out;

  const size_t MBb = 1024ull * 1024ull;
  char* w = (char*)d_ws;
  float* qb = (float*)(w + 0 * MBb);     // 16 MB each
  float* kb = (float*)(w + 16 * MBb);
  float* vb = (float*)(w + 32 * MBb);
  float* ob = (float*)(w + 48 * MBb);
  unsigned short* xhi    = (unsigned short*)(w + 64 * MBb);   // 8 MB each
  unsigned short* xlo    = (unsigned short*)(w + 72 * MBb);
  unsigned short* wqt    = (unsigned short*)(w + 80 * MBb);
  unsigned short* wkt_hi = (unsigned short*)(w + 88 * MBb);
  unsigned short* wkt_lo = (unsigned short*)(w + 96 * MBb);
  unsigned short* wvt_hi = (unsigned short*)(w + 104 * MBb);
  unsigned short* wvt_lo = (unsigned short*)(w + 112 * MBb);
  unsigned short* wot    = (unsigned short*)(w + 120 * MBb);
  unsigned short* ohi    = xhi;  // x is dead after the kv GEMMs; reuse

  const int n8 = (NROWS * DM) / 8;       // 524288 vec8 groups
  dim3 tgrid(DM / 64, DM / 64);          // weight transpose tiles
  dim3 ggrid(DM / 128, NROWS / 128);     // 16 x 16 GEMM tiles

  // Convert / transpose inputs to bf16 (hi/lo where the quantizer demands it)
  split_convert_kernel<<<n8 / 256, 256, 0, stream>>>(x, xhi, xlo, n8);
  transpose_split_kernel<<<tgrid, 256, 0, stream>>>(Wq, wqt, nullptr, DM, DM);
  transpose_split_kernel<<<tgrid, 256, 0, stream>>>(Wk, wkt_hi, wkt_lo, DM, DM);
  transpose_split_kernel<<<tgrid, 256, 0, stream>>>(Wv, wvt_hi, wvt_lo, DM, DM);
  transpose_split_kernel<<<tgrid, 256, 0, stream>>>(Wo, wot, nullptr, DM, DM);

  // Projections: q plain-bf16, k/v split-bf16 (quantizer downstream)
  gemm_mfma_kernel<false><<<ggrid, 256, 0, stream>>>(xhi, nullptr, wqt, nullptr, qb, NROWS, DM, DM);
  gemm_mfma_kernel<true ><<<ggrid, 256, 0, stream>>>(xhi, xlo, wkt_hi, wkt_lo, kb, NROWS, DM, DM);
  gemm_mfma_kernel<true ><<<ggrid, 256, 0, stream>>>(xhi, xlo, wvt_hi, wvt_lo, vb, NROWS, DM, DM);

  rmsnorm_kernel<<<NROWS, 256, 0, stream>>>(qb, qn_w);
  rmsnorm_kernel<<<NROWS, 256, 0, stream>>>(kb, kn_w);
  quant_kernel<<<NVEC / 256, 256, 0, stream>>>(kb, Mk, Mtk, Ck);
  quant_kernel<<<NVEC / 256, 256, 0, stream>>>(vb, Mv, Mtv, Cv);

  flash_attn_kernel<<<BATCH * HEADS * SEQ / 64, 256, 0, stream>>>(qb, kb, vb, ob);

  // Output projection: plain bf16
  split_convert_kernel<<<n8 / 256, 256, 0, stream>>>(ob, ohi, nullptr, n8);
  gemm_mfma_kernel<false><<<ggrid, 256, 0, stream>>>(ohi, nullptr, wot, nullptr, out, NROWS, DM, DM);
}

// Round 4
// 563.253 us; speedup vs baseline: 10.4516x; 1.2744x over previous
//
#include <hip/hip_runtime.h>
#include <hip/hip_bf16.h>
#include <math.h>

// Problem constants (fixed by the reference)
#define HEADS 32
#define DIM_HEAD 64
#define DM 2048          // HEADS * DIM_HEAD
#define BATCH 2
#define SEQ 1024
#define NROWS (BATCH * SEQ)      // 2048 rows of DM
#define NVEC (NROWS * HEADS)     // 65536 per-head vectors
#define N_GROUPS 22
#define N_LEVELS 8
#define EPS_NORM 1e-8f
#define EPS_RMS 1e-6f

typedef float f32x4 __attribute__((ext_vector_type(4)));
typedef __bf16 bf16x8 __attribute__((ext_vector_type(8)));
typedef unsigned short u16x8 __attribute__((ext_vector_type(8)));
typedef unsigned short u16x4 __attribute__((ext_vector_type(4)));

__device__ __forceinline__ unsigned short f2bf(float x) {
  union { float f; unsigned u; } v; v.f = x;
  unsigned r = v.u + 0x7fffu + ((v.u >> 16) & 1u);  // RTN-even
  return (unsigned short)(r >> 16);
}
__device__ __forceinline__ float bf2f(unsigned short h) {
  union { unsigned u; float f; } v; v.u = ((unsigned)h) << 16;
  return v.f;
}
__device__ __forceinline__ bf16x8 ldfrag(const unsigned short* p) {
  return __builtin_bit_cast(bf16x8, *(const u16x8*)p);
}
#define MFMA16(a, b, c) __builtin_amdgcn_mfma_f32_16x16x32_bf16((a), (b), (c), 0, 0, 0)

// ---------------------------------------------------------------------------
// fp32 -> bf16 hi/lo split (lo optional), 8 elements/thread
// ---------------------------------------------------------------------------
__global__ __launch_bounds__(256) void split_convert_kernel(
    const float* __restrict__ X, unsigned short* __restrict__ hi,
    unsigned short* __restrict__ lo, int n8) {
  const int i = blockIdx.x * 256 + threadIdx.x;
  if (i >= n8) return;
  const float4 a = ((const float4*)X)[2 * i];
  const float4 b = ((const float4*)X)[2 * i + 1];
  const float v[8] = {a.x, a.y, a.z, a.w, b.x, b.y, b.z, b.w};
  u16x8 h, l;
#pragma unroll
  for (int j = 0; j < 8; ++j) {
    const unsigned short hh = f2bf(v[j]);
    h[j] = hh;
    l[j] = f2bf(v[j] - bf2f(hh));
  }
  ((u16x8*)hi)[i] = h;
  if (lo) ((u16x8*)lo)[i] = l;
}

// ---------------------------------------------------------------------------
// W [K][M] fp32 -> Th/Tl [M][K] bf16 hi/lo (transpose + split; lo optional)
// ---------------------------------------------------------------------------
__global__ __launch_bounds__(256) void transpose_split_kernel(
    const float* __restrict__ W, unsigned short* __restrict__ Th,
    unsigned short* __restrict__ Tl, int K, int M) {
  __shared__ float S[64][65];
  const int t = threadIdx.x;
  const int tk = blockIdx.y * 64, tm = blockIdx.x * 64;
  {
    const int r = t >> 2, cs = (t & 3) * 16;
    const float* src = W + (size_t)(tk + r) * M + tm + cs;
#pragma unroll
    for (int j = 0; j < 16; j += 4) {
      float4 v = *(const float4*)(src + j);
      S[r][cs + j] = v.x; S[r][cs + j + 1] = v.y;
      S[r][cs + j + 2] = v.z; S[r][cs + j + 3] = v.w;
    }
  }
  __syncthreads();
  const int m = t >> 2, ks = (t & 3) * 16;
  u16x8 h0, h1, l0, l1;
#pragma unroll
  for (int j = 0; j < 8; ++j) {
    const float v = S[ks + j][m];
    const unsigned short hh = f2bf(v);
    h0[j] = hh; l0[j] = f2bf(v - bf2f(hh));
  }
#pragma unroll
  for (int j = 0; j < 8; ++j) {
    const float v = S[ks + 8 + j][m];
    const unsigned short hh = f2bf(v);
    h1[j] = hh; l1[j] = f2bf(v - bf2f(hh));
  }
  const size_t o = (size_t)(tm + m) * K + tk + ks;
  *(u16x8*)&Th[o] = h0; *(u16x8*)&Th[o + 8] = h1;
  if (Tl) { *(u16x8*)&Tl[o] = l0; *(u16x8*)&Tl[o + 8] = l1; }
}

// ---------------------------------------------------------------------------
// MFMA GEMM (m97 recipe): C[N,M] = A[N,K] @ Bt[M,K]^T, bf16 in, fp32 acc.
// ---------------------------------------------------------------------------
__device__ __forceinline__ void stage16(const unsigned short* g, unsigned short* lds) {
  __builtin_amdgcn_global_load_lds(
      (const __attribute__((address_space(1))) unsigned int*)g,
      (__attribute__((address_space(3))) unsigned int*)lds, 16, 0, 0);
}

template <bool SPLIT>
__global__ __launch_bounds__(256) void gemm_mfma_kernel(
    const unsigned short* __restrict__ Ahi, const unsigned short* __restrict__ Alo,
    const unsigned short* __restrict__ Bhi, const unsigned short* __restrict__ Blo,
    float* __restrict__ C, int N, int K, int M) {
  __shared__ unsigned short lAhi[128 * 32];
  __shared__ unsigned short lBhi[128 * 32];
  __shared__ unsigned short lAlo[SPLIT ? 128 * 32 : 8];
  __shared__ unsigned short lBlo[SPLIT ? 128 * 32 : 8];

  const int t = threadIdx.x;
  const int lane = t & 63, wave = t >> 6;
  const int wr = wave >> 1, wc = wave & 1;
  const int gm0 = blockIdx.y * 128, gn0 = blockIdx.x * 128;
  const int lrsub = lane >> 2;
  const int lcsub = lane & 3;

  f32x4 acc[4][4] = {};

  for (int kt = 0; kt < K; kt += 32) {
    __syncthreads();
#pragma unroll
    for (int rg = wave; rg < 8; rg += 4) {
      const int lrow = rg * 16 + lrsub;
      const int c = lcsub ^ ((lrow >> 1) & 3);
      const size_t goffA = (size_t)(gm0 + lrow) * K + kt + c * 8;
      const size_t goffB = (size_t)(gn0 + lrow) * K + kt + c * 8;
      stage16(Ahi + goffA, lAhi + rg * 512);
      stage16(Bhi + goffB, lBhi + rg * 512);
      if (SPLIT) {
        stage16(Alo + goffA, lAlo + rg * 512);
        stage16(Blo + goffB, lBlo + rg * 512);
      }
    }
    __syncthreads();

    bf16x8 ah[4], bh[4], al[4], bl[4];
#pragma unroll
    for (int i = 0; i < 4; ++i) {
      const int mrow = wr * 64 + i * 16 + (lane & 15);
      const int offa = mrow * 32 + (((lane >> 4) ^ ((mrow >> 1) & 3)) << 3);
      ah[i] = ldfrag(&lAhi[offa]);
      if (SPLIT) al[i] = ldfrag(&lAlo[offa]);
      const int nrow = wc * 64 + i * 16 + (lane & 15);
      const int offb = nrow * 32 + (((lane >> 4) ^ ((nrow >> 1) & 3)) << 3);
      bh[i] = ldfrag(&lBhi[offb]);
      if (SPLIT) bl[i] = ldfrag(&lBlo[offb]);
    }
#pragma unroll
    for (int i = 0; i < 4; ++i)
#pragma unroll
      for (int j = 0; j < 4; ++j) {
        acc[i][j] = MFMA16(ah[i], bh[j], acc[i][j]);
        if (SPLIT) {
          acc[i][j] = MFMA16(ah[i], bl[j], acc[i][j]);
          acc[i][j] = MFMA16(al[i], bh[j], acc[i][j]);
        }
      }
  }

#pragma unroll
  for (int i = 0; i < 4; ++i) {
    const int row = gm0 + wr * 64 + i * 16 + ((lane >> 4) << 2);
#pragma unroll
    for (int j = 0; j < 4; ++j) {
      const int col = gn0 + wc * 64 + j * 16 + (lane & 15);
#pragma unroll
      for (int r = 0; r < 4; ++r)
        C[(size_t)(row + r) * M + col] = acc[i][j][r];
    }
  }
}

// ---------------------------------------------------------------------------
// Wave reductions
// ---------------------------------------------------------------------------
__device__ __forceinline__ float wave_sum(float x) {
#pragma unroll
  for (int o = 32; o > 0; o >>= 1) x += __shfl_xor(x, o, 64);
  return x;
}

// ---------------------------------------------------------------------------
// RMSNorm in place (fp32), one block per row.  (k path)
// ---------------------------------------------------------------------------
__global__ __launch_bounds__(256) void rmsnorm_kernel(
    float* __restrict__ y, const float* __restrict__ w) {
  __shared__ float rbuf[4];
  const int row = blockIdx.x;
  float* p = y + (size_t)row * DM;
  const int t = threadIdx.x;
  const int wave = t >> 6, lane = t & 63;

  float ss = 0.f;
#pragma unroll
  for (int c = t; c < DM; c += 256) { float v = p[c]; ss += v * v; }
  ss = wave_sum(ss);
  if (lane == 0) rbuf[wave] = ss;
  __syncthreads();
  ss = rbuf[0] + rbuf[1] + rbuf[2] + rbuf[3];
  const float scale = rsqrtf(ss * (1.0f / DM) + EPS_RMS);
#pragma unroll
  for (int c = t; c < DM; c += 256) p[c] = p[c] * scale * w[c];
}

// ---------------------------------------------------------------------------
// RMSNorm -> bf16 hi/lo with extra post-scale (q path: folds 1/8)
// ---------------------------------------------------------------------------
__global__ __launch_bounds__(256) void rmsnorm_split_kernel(
    const float* __restrict__ y, const float* __restrict__ w,
    unsigned short* __restrict__ hi, unsigned short* __restrict__ lo,
    float post) {
  __shared__ float rbuf[4];
  const int row = blockIdx.x;
  const float* p = y + (size_t)row * DM;
  const int t = threadIdx.x;
  const int wave = t >> 6, lane = t & 63;

  const int c0 = t * 8;
  float4 a = *(const float4*)(p + c0);
  float4 b = *(const float4*)(p + c0 + 4);
  float v[8] = {a.x, a.y, a.z, a.w, b.x, b.y, b.z, b.w};
  float ss = 0.f;
#pragma unroll
  for (int j = 0; j < 8; ++j) ss += v[j] * v[j];
  ss = wave_sum(ss);
  if (lane == 0) rbuf[wave] = ss;
  __syncthreads();
  ss = rbuf[0] + rbuf[1] + rbuf[2] + rbuf[3];
  const float scale = rsqrtf(ss * (1.0f / DM) + EPS_RMS) * post;

  u16x8 hv, lv;
#pragma unroll
  for (int j = 0; j < 8; ++j) {
    const float val = v[j] * scale * w[c0 + j];
    const unsigned short hh = f2bf(val);
    hv[j] = hh; lv[j] = f2bf(val - bf2f(hh));
  }
  *(u16x8*)&hi[(size_t)row * DM + c0] = hv;
  *(u16x8*)&lo[(size_t)row * DM + c0] = lv;
}

// ---------------------------------------------------------------------------
// RotorQuant roundtrip. WRITE_BF: emit bf16 hi/lo; else fp32 in place.
// ---------------------------------------------------------------------------
__device__ __forceinline__ float qnearest(float v, const float* __restrict__ C) {
  float best = C[0];
  float bd = fabsf(v - C[0]);
#pragma unroll
  for (int i = 1; i < N_LEVELS; ++i) {
    float d = fabsf(v - C[i]);
    if (d < bd) { bd = d; best = C[i]; }
  }
  return best;
}

template <bool WRITE_BF>
__global__ __launch_bounds__(256) void quant_kernel(
    float* __restrict__ kv, const float* __restrict__ M,
    const float* __restrict__ Mt, const float* __restrict__ C,
    unsigned short* __restrict__ hi, unsigned short* __restrict__ lo) {
  const int vec = blockIdx.x * blockDim.x + threadIdx.x;
  if (vec >= NVEC) return;
  float* p = kv + (size_t)vec * DIM_HEAD;

  float h[66];
  float ss = 0.f;
#pragma unroll
  for (int d = 0; d < DIM_HEAD; ++d) { h[d] = p[d]; ss += h[d] * h[d]; }
  float norm = fmaxf(sqrtf(ss), EPS_NORM);
  const float inv = 1.0f / norm;
#pragma unroll
  for (int d = 0; d < DIM_HEAD; ++d) h[d] *= inv;
  h[64] = 0.f; h[65] = 0.f;

#pragma unroll
  for (int g = 0; g < N_GROUPS; ++g) {
    const float* Mg  = M  + g * 9;
    const float* Mtg = Mt + g * 9;
    const float a0 = h[3 * g + 0], a1 = h[3 * g + 1], a2 = h[3 * g + 2];
    const float r0 = a0 * Mg[0] + a1 * Mg[3] + a2 * Mg[6];
    const float r1 = a0 * Mg[1] + a1 * Mg[4] + a2 * Mg[7];
    const float r2 = a0 * Mg[2] + a1 * Mg[5] + a2 * Mg[8];
    const float d0 = qnearest(r0, C);
    const float d1 = qnearest(r1, C);
    const float d2 = qnearest(r2, C);
    h[3 * g + 0] = d0 * Mtg[0] + d1 * Mtg[3] + d2 * Mtg[6];
    h[3 * g + 1] = d0 * Mtg[1] + d1 * Mtg[4] + d2 * Mtg[7];
    h[3 * g + 2] = d0 * Mtg[2] + d1 * Mtg[5] + d2 * Mtg[8];
  }
  if (WRITE_BF) {
#pragma unroll
    for (int g8 = 0; g8 < 8; ++g8) {
      u16x8 hv, lv;
#pragma unroll
      for (int j = 0; j < 8; ++j) {
        const float val = h[g8 * 8 + j] * norm;
        const unsigned short hh = f2bf(val);
        hv[j] = hh; lv[j] = f2bf(val - bf2f(hh));
      }
      *(u16x8*)&hi[(size_t)vec * DIM_HEAD + g8 * 8] = hv;
      *(u16x8*)&lo[(size_t)vec * DIM_HEAD + g8 * 8] = lv;
    }
  } else {
#pragma unroll
    for (int d = 0; d < DIM_HEAD; ++d) p[d] = h[d] * norm;
  }
}

// ---------------------------------------------------------------------------
// Per-head V transpose + split: v[b][s][h*64+d] fp32 -> vt[(bh*64+d)][s] hi/lo
// Grid: (16 s-tiles, 64 bh); 256 threads.
// ---------------------------------------------------------------------------
__global__ __launch_bounds__(256) void vt_split_kernel(
    const float* __restrict__ v, unsigned short* __restrict__ hi,
    unsigned short* __restrict__ lo) {
  __shared__ float T[64][65];
  const int s0 = blockIdx.x * 64;
  const int bh = blockIdx.y;
  const int b = bh >> 5, h = bh & 31;
  const int t = threadIdx.x;
  {
    const int sr = t >> 2, dseg = (t & 3) * 16;
    const float* src = v + ((size_t)(b * SEQ + s0 + sr) * DM + h * 64 + dseg);
#pragma unroll
    for (int j = 0; j < 16; j += 4) {
      float4 a = *(const float4*)(src + j);
      T[sr][dseg + j] = a.x; T[sr][dseg + j + 1] = a.y;
      T[sr][dseg + j + 2] = a.z; T[sr][dseg + j + 3] = a.w;
    }
  }
  __syncthreads();
  const int d = t >> 2, sseg = (t & 3) * 16;
  u16x8 h0, h1, l0, l1;
#pragma unroll
  for (int j = 0; j < 8; ++j) {
    const float val = T[sseg + j][d];
    const unsigned short hh = f2bf(val);
    h0[j] = hh; l0[j] = f2bf(val - bf2f(hh));
  }
#pragma unroll
  for (int j = 0; j < 8; ++j) {
    const float val = T[sseg + 8 + j][d];
    const unsigned short hh = f2bf(val);
    h1[j] = hh; l1[j] = f2bf(val - bf2f(hh));
  }
  const size_t o = (size_t)(bh * 64 + d) * SEQ + s0 + sseg;
  *(u16x8*)&hi[o] = h0; *(u16x8*)&hi[o + 8] = h1;
  *(u16x8*)&lo[o] = l0; *(u16x8*)&lo[o + 8] = l1;
}

// ---------------------------------------------------------------------------
// MFMA flash attention, split-bf16. Block = (b,h,64-q rows), 256 threads.
// Wave w owns q rows [w*16, w*16+16): S tile 16x64 (C-layout), online
// softmax wave-local, O^T tile 64d x 16q. P roundtrips through wave-private
// LDS rows. All LDS arrays [64 rows][64 u16], chunk-XOR swizzled (2-way = free).
// ---------------------------------------------------------------------------
__global__ __launch_bounds__(256) void attn_mfma_kernel(
    const unsigned short* __restrict__ qhi, const unsigned short* __restrict__ qlo,
    const unsigned short* __restrict__ khi, const unsigned short* __restrict__ klo,
    const unsigned short* __restrict__ vthi, const unsigned short* __restrict__ vtlo,
    unsigned short* __restrict__ ohi) {
  __shared__ unsigned short Ks_h[4096], Ks_l[4096];
  __shared__ unsigned short Vt_h[4096], Vt_l[4096];
  __shared__ unsigned short Ps_h[4096], Ps_l[4096];
  __shared__ float alpha_s[4][16];
  __shared__ float l_s[4][16];

  const int qt = blockIdx.x;        // 0..15
  const int bh = blockIdx.y;        // 0..63
  const int h = bh & 31, b = bh >> 5;
  const int q0 = qt * 64;
  const int t = threadIdx.x, lane = t & 63, w = t >> 6;
  const int quad = lane >> 4, l15 = lane & 15;
  const int srow = lane >> 3, schunk = lane & 7;

  // wave w stages rows [w*16, w*16+16) of a [64][64u16] tile
  auto stage = [&](const unsigned short* g, int stride, unsigned short* arr) {
#pragma unroll
    for (int it = 0; it < 2; ++it) {
      const int r = w * 16 + it * 8 + srow;
      const int c = schunk ^ (r & 7);
      stage16(g + (size_t)r * stride + c * 8, arr + (w * 16 + it * 8) * 64);
    }
  };

  // ---- Q preload (reuse Ps buffers), A-frag rows = w*16 + l15
  stage(qhi + ((size_t)(b * SEQ + q0) * DM + h * 64), DM, Ps_h);
  stage(qlo + ((size_t)(b * SEQ + q0) * DM + h * 64), DM, Ps_l);
  __syncthreads();
  bf16x8 qh[2], ql[2];
#pragma unroll
  for (int ks = 0; ks < 2; ++ks) {
    const int row = w * 16 + l15;
    const int off = row * 64 + (((quad + 4 * ks) ^ (row & 7)) << 3);
    qh[ks] = ldfrag(&Ps_h[off]);
    ql[ks] = ldfrag(&Ps_l[off]);
  }

  f32x4 acc[4] = {};                       // O^T: rows d = mt*16+quad*4+reg, col q = w*16+l15
  float m_prev[4] = {-INFINITY, -INFINITY, -INFINITY, -INFINITY};
  float lsum[4] = {0.f, 0.f, 0.f, 0.f};

  const unsigned short* gkh = khi + ((size_t)(b * SEQ) * DM + h * 64);
  const unsigned short* gkl = klo + ((size_t)(b * SEQ) * DM + h * 64);
  const unsigned short* gvh = vthi + (size_t)(bh * 64) * SEQ;
  const unsigned short* gvl = vtlo + (size_t)(bh * 64) * SEQ;

  for (int kt = 0; kt < SEQ; kt += 64) {
    __syncthreads();                       // prev iter's K/Vt frag reads done
    stage(gkh + (size_t)kt * DM, DM, Ks_h);
    stage(gkl + (size_t)kt * DM, DM, Ks_l);
    stage(gvh + kt, SEQ, Vt_h);
    stage(gvl + kt, SEQ, Vt_l);
    __syncthreads();                       // staging drained

    // ---- S = (Q/8) @ K^T, split: Qh*Kh + Qh*Kl + Ql*Kh
    f32x4 s[4] = {};
#pragma unroll
    for (int nt = 0; nt < 4; ++nt) {
#pragma unroll
      for (int ks = 0; ks < 2; ++ks) {
        const int row = nt * 16 + l15;
        const int off = row * 64 + (((quad + 4 * ks) ^ (row & 7)) << 3);
        const bf16x8 kh = ldfrag(&Ks_h[off]);
        const bf16x8 kl = ldfrag(&Ks_l[off]);
        s[nt] = MFMA16(qh[ks], kh, s[nt]);
        s[nt] = MFMA16(qh[ks], kl, s[nt]);
        s[nt] = MFMA16(ql[ks], kh, s[nt]);
      }
    }

    // ---- online softmax per q row (C-layout row = quad*4 + r)
    float asave[4];
#pragma unroll
    for (int r = 0; r < 4; ++r) {
      float mx = fmaxf(fmaxf(s[0][r], s[1][r]), fmaxf(s[2][r], s[3][r]));
#pragma unroll
      for (int off = 1; off < 16; off <<= 1) mx = fmaxf(mx, __shfl_xor(mx, off, 64));
      const float mn = fmaxf(m_prev[r], mx);
      const float al = __expf(m_prev[r] - mn);
      float rs = 0.f;
#pragma unroll
      for (int nt = 0; nt < 4; ++nt) {
        const float e = __expf(s[nt][r] - mn);
        s[nt][r] = e; rs += e;
      }
#pragma unroll
      for (int off = 1; off < 16; off <<= 1) rs += __shfl_xor(rs, off, 64);
      lsum[r] = lsum[r] * al + rs;
      m_prev[r] = mn;
      asave[r] = al;
      // P row write (wave-private rows): split to bf16 hi/lo
      const int prow = w * 16 + quad * 4 + r;
#pragma unroll
      for (int nt = 0; nt < 4; ++nt) {
        const int kk = nt * 16 + l15;
        const int off2 = prow * 64 + (((kk >> 3) ^ (prow & 7)) << 3) + (kk & 7);
        const unsigned short hh = f2bf(s[nt][r]);
        Ps_h[off2] = hh;
        Ps_l[off2] = f2bf(s[nt][r] - bf2f(hh));
      }
    }

    // ---- broadcast alpha to O^T lanes (col q = l15) and rescale acc
    if (l15 == 0) {
#pragma unroll
      for (int r = 0; r < 4; ++r) alpha_s[w][quad * 4 + r] = asave[r];
    }
    const float alph = alpha_s[w][l15];    // same-wave DS ordering
#pragma unroll
    for (int mt = 0; mt < 4; ++mt) acc[mt] *= alph;

    // ---- O^T += V^T @ P^T-as-B: A = Vt frags, B = P frags
#pragma unroll
    for (int mt = 0; mt < 4; ++mt) {
#pragma unroll
      for (int ks = 0; ks < 2; ++ks) {
        const int drow = mt * 16 + l15;
        const int offv = drow * 64 + (((quad + 4 * ks) ^ (drow & 7)) << 3);
        const bf16x8 vh = ldfrag(&Vt_h[offv]);
        const bf16x8 vl = ldfrag(&Vt_l[offv]);
        const int prow = w * 16 + l15;
        const int offp = prow * 64 + (((quad + 4 * ks) ^ (prow & 7)) << 3);
        const bf16x8 ph = ldfrag(&Ps_h[offp]);
        const bf16x8 pl = ldfrag(&Ps_l[offp]);
        acc[mt] = MFMA16(vh, ph, acc[mt]);
        acc[mt] = MFMA16(vh, pl, acc[mt]);
        acc[mt] = MFMA16(vl, ph, acc[mt]);
      }
    }
  }

  // ---- epilogue: divide by l (per col q = l15), write bf16 O
  if (l15 == 0) {
#pragma unroll
    for (int r = 0; r < 4; ++r) l_s[w][quad * 4 + r] = lsum[r];
  }
  const float inv = 1.0f / l_s[w][l15];
  const size_t obase = (size_t)(b * SEQ + q0 + w * 16 + l15) * DM + h * 64;
#pragma unroll
  for (int mt = 0; mt < 4; ++mt) {
    u16x4 ov;
#pragma unroll
    for (int r = 0; r < 4; ++r) ov[r] = f2bf(acc[mt][r] * inv);
    *(u16x4*)&ohi[obase + mt * 16 + quad * 4] = ov;
  }
}

// ---------------------------------------------------------------------------
// Launch
// ---------------------------------------------------------------------------
extern "C" void kernel_launch(void* const* d_in, const int* in_sizes, int n_in,
                              void* d_out, int out_size, void* d_ws, size_t ws_size,
                              hipStream_t stream) {
  const float* x    = (const float*)d_in[0];
  const float* Wq   = (const float*)d_in[1];
  const float* Wk   = (const float*)d_in[2];
  const float* Wv   = (const float*)d_in[3];
  const float* Wo   = (const float*)d_in[4];
  const float* qn_w = (const float*)d_in[5];
  const float* kn_w = (const float*)d_in[6];
  const float* Mk   = (const float*)d_in[7];
  const float* Mtk  = (const float*)d_in[8];
  const float* Ck   = (const float*)d_in[9];
  const float* Mv   = (const float*)d_in[10];
  const float* Mtv  = (const float*)d_in[11];
  const float* Cv   = (const float*)d_in[12];
  float* out = (float*)d_out;

  const size_t MBb = 1024ull * 1024ull;
  char* w = (char*)d_ws;
  float* qb = (float*)(w + 0 * MBb);      // 16 MB each
  float* kb = (float*)(w + 16 * MBb);
  float* vb = (float*)(w + 32 * MBb);
  unsigned short* xhi    = (unsigned short*)(w + 48 * MBb);   // 8 MB each
  unsigned short* xlo    = (unsigned short*)(w + 56 * MBb);
  unsigned short* wqt    = (unsigned short*)(w + 64 * MBb);
  unsigned short* wkt_hi = (unsigned short*)(w + 72 * MBb);
  unsigned short* wkt_lo = (unsigned short*)(w + 80 * MBb);
  unsigned short* wvt_hi = (unsigned short*)(w + 88 * MBb);
  unsigned short* wvt_lo = (unsigned short*)(w + 96 * MBb);
  unsigned short* wot    = (unsigned short*)(w + 104 * MBb);
  // Reuse after the projection GEMMs complete:
  unsigned short* q_hi = wqt;      // wqt dead after q GEMM
  unsigned short* q_lo = xhi;      // x dead after v GEMM
  unsigned short* k_hi = wkt_hi;   // dead after k GEMM
  unsigned short* k_lo = wkt_lo;
  unsigned short* vt_hi = wvt_hi;  // dead after v GEMM
  unsigned short* vt_lo = wvt_lo;
  unsigned short* o_hi = xlo;      // x dead

  const int n8 = (NROWS * DM) / 8;
  dim3 tgrid(DM / 64, DM / 64);
  dim3 ggrid(DM / 128, NROWS / 128);

  split_convert_kernel<<<n8 / 256, 256, 0, stream>>>(x, xhi, xlo, n8);
  transpose_split_kernel<<<tgrid, 256, 0, stream>>>(Wq, wqt, nullptr, DM, DM);
  transpose_split_kernel<<<tgrid, 256, 0, stream>>>(Wk, wkt_hi, wkt_lo, DM, DM);
  transpose_split_kernel<<<tgrid, 256, 0, stream>>>(Wv, wvt_hi, wvt_lo, DM, DM);
  transpose_split_kernel<<<tgrid, 256, 0, stream>>>(Wo, wot, nullptr, DM, DM);

  gemm_mfma_kernel<false><<<ggrid, 256, 0, stream>>>(xhi, nullptr, wqt, nullptr, qb, NROWS, DM, DM);
  gemm_mfma_kernel<true ><<<ggrid, 256, 0, stream>>>(xhi, xlo, wkt_hi, wkt_lo, kb, NROWS, DM, DM);
  gemm_mfma_kernel<true ><<<ggrid, 256, 0, stream>>>(xhi, xlo, wvt_hi, wvt_lo, vb, NROWS, DM, DM);

  rmsnorm_kernel<<<NROWS, 256, 0, stream>>>(kb, kn_w);
  rmsnorm_split_kernel<<<NROWS, 256, 0, stream>>>(qb, qn_w, q_hi, q_lo, 0.125f);

  quant_kernel<true ><<<NVEC / 256, 256, 0, stream>>>(kb, Mk, Mtk, Ck, k_hi, k_lo);
  quant_kernel<false><<<NVEC / 256, 256, 0, stream>>>(vb, Mv, Mtv, Cv, nullptr, nullptr);
  vt_split_kernel<<<dim3(SEQ / 64, BATCH * HEADS), 256, 0, stream>>>(vb, vt_hi, vt_lo);

  attn_mfma_kernel<<<dim3(SEQ / 64, BATCH * HEADS), 256, 0, stream>>>(
      q_hi, q_lo, k_hi, k_lo, vt_hi, vt_lo, o_hi);

  gemm_mfma_kernel<false><<<ggrid, 256, 0, stream>>>(o_hi, nullptr, wot, nullptr, out, NROWS, DM, DM);
}

// Round 5
// 482.298 us; speedup vs baseline: 12.2060x; 1.1679x over previous
//
#include <hip/hip_runtime.h>
#include <hip/hip_bf16.h>
#include <math.h>

// Problem constants (fixed by the reference)
#define HEADS 32
#define DIM_HEAD 64
#define DM 2048          // HEADS * DIM_HEAD
#define BATCH 2
#define SEQ 1024
#define NROWS (BATCH * SEQ)      // 2048 rows of DM
#define NVEC (NROWS * HEADS)     // 65536 per-head vectors
#define N_GROUPS 22
#define N_LEVELS 8
#define EPS_NORM 1e-8f
#define EPS_RMS 1e-6f

typedef float f32x4 __attribute__((ext_vector_type(4)));
typedef __bf16 bf16x8 __attribute__((ext_vector_type(8)));
typedef unsigned short u16x8 __attribute__((ext_vector_type(8)));
typedef unsigned short u16x4 __attribute__((ext_vector_type(4)));

__device__ __forceinline__ unsigned short f2bf(float x) {
  union { float f; unsigned u; } v; v.f = x;
  unsigned r = v.u + 0x7fffu + ((v.u >> 16) & 1u);  // RTN-even
  return (unsigned short)(r >> 16);
}
__device__ __forceinline__ float bf2f(unsigned short h) {
  union { unsigned u; float f; } v; v.u = ((unsigned)h) << 16;
  return v.f;
}
__device__ __forceinline__ bf16x8 ldfrag(const unsigned short* p) {
  return __builtin_bit_cast(bf16x8, *(const u16x8*)p);
}
#define MFMA16(a, b, c) __builtin_amdgcn_mfma_f32_16x16x32_bf16((a), (b), (c), 0, 0, 0)

__device__ __forceinline__ void stage16(const unsigned short* g, unsigned short* lds) {
  __builtin_amdgcn_global_load_lds(
      (const __attribute__((address_space(1))) unsigned int*)g,
      (__attribute__((address_space(3))) unsigned int*)lds, 16, 0, 0);
}

// ---------------------------------------------------------------------------
// fp32 -> bf16 hi/lo split (lo optional), 8 elements/thread
// ---------------------------------------------------------------------------
__global__ __launch_bounds__(256) void split_convert_kernel(
    const float* __restrict__ X, unsigned short* __restrict__ hi,
    unsigned short* __restrict__ lo, int n8) {
  const int i = blockIdx.x * 256 + threadIdx.x;
  if (i >= n8) return;
  const float4 a = ((const float4*)X)[2 * i];
  const float4 b = ((const float4*)X)[2 * i + 1];
  const float v[8] = {a.x, a.y, a.z, a.w, b.x, b.y, b.z, b.w};
  u16x8 h, l;
#pragma unroll
  for (int j = 0; j < 8; ++j) {
    const unsigned short hh = f2bf(v[j]);
    h[j] = hh;
    l[j] = f2bf(v[j] - bf2f(hh));
  }
  ((u16x8*)hi)[i] = h;
  if (lo) ((u16x8*)lo)[i] = l;
}

// ---------------------------------------------------------------------------
// Batched weight transpose+split: W [K][M] fp32 -> T [M][K] bf16 hi(/lo).
// grid (M/64, K/64, 4): z selects {Wq, Wk, Wv, Wo}.
// ---------------------------------------------------------------------------
__global__ __launch_bounds__(256) void transpose_split_batch_kernel(
    const float* __restrict__ W0, const float* __restrict__ W1,
    const float* __restrict__ W2, const float* __restrict__ W3,
    unsigned short* __restrict__ T0h, unsigned short* __restrict__ T1h,
    unsigned short* __restrict__ T1l, unsigned short* __restrict__ T2h,
    unsigned short* __restrict__ T2l, unsigned short* __restrict__ T3h) {
  const int z = blockIdx.z;
  const float* W = (z == 0) ? W0 : (z == 1) ? W1 : (z == 2) ? W2 : W3;
  unsigned short* Th = (z == 0) ? T0h : (z == 1) ? T1h : (z == 2) ? T2h : T3h;
  unsigned short* Tl = (z == 1) ? T1l : (z == 2) ? T2l : nullptr;

  __shared__ float S[64][65];
  const int t = threadIdx.x;
  const int tk = blockIdx.y * 64, tm = blockIdx.x * 64;
  {
    const int r = t >> 2, cs = (t & 3) * 16;
    const float* src = W + (size_t)(tk + r) * DM + tm + cs;
#pragma unroll
    for (int j = 0; j < 16; j += 4) {
      float4 v = *(const float4*)(src + j);
      S[r][cs + j] = v.x; S[r][cs + j + 1] = v.y;
      S[r][cs + j + 2] = v.z; S[r][cs + j + 3] = v.w;
    }
  }
  __syncthreads();
  const int m = t >> 2, ks = (t & 3) * 16;
  u16x8 h0, h1, l0, l1;
#pragma unroll
  for (int j = 0; j < 8; ++j) {
    const float v = S[ks + j][m];
    const unsigned short hh = f2bf(v);
    h0[j] = hh; l0[j] = f2bf(v - bf2f(hh));
  }
#pragma unroll
  for (int j = 0; j < 8; ++j) {
    const float v = S[ks + 8 + j][m];
    const unsigned short hh = f2bf(v);
    h1[j] = hh; l1[j] = f2bf(v - bf2f(hh));
  }
  const size_t o = (size_t)(tm + m) * DM + tk + ks;
  *(u16x8*)&Th[o] = h0; *(u16x8*)&Th[o + 8] = h1;
  if (Tl) { *(u16x8*)&Tl[o] = l0; *(u16x8*)&Tl[o + 8] = l1; }
}

// ---------------------------------------------------------------------------
// Fused QKV GEMM: A[N=2048][K=2048] @ Bcat[M=6144][K]^T, where Bcat rows
// 0..2047 = Wq^T (plain bf16), 2048..4095 = Wk^T, 4096..6143 = Wv^T (split).
// 128x128 tile; grid (48, 16) = 768 blocks (3/CU). Per-block plain/split
// branch (block-uniform). Outputs route to q/k/v buffers [2048][2048] fp32.
// ---------------------------------------------------------------------------
__global__ __launch_bounds__(256) void qkv_gemm_kernel(
    const unsigned short* __restrict__ Ahi, const unsigned short* __restrict__ Alo,
    const unsigned short* __restrict__ Bhi, const unsigned short* __restrict__ Blo,
    float* __restrict__ q, float* __restrict__ k, float* __restrict__ v) {
  __shared__ unsigned short lAhi[128 * 32];
  __shared__ unsigned short lBhi[128 * 32];
  __shared__ unsigned short lAlo[128 * 32];
  __shared__ unsigned short lBlo[128 * 32];

  const int t = threadIdx.x;
  const int lane = t & 63, wave = t >> 6;
  const int wr = wave >> 1, wc = wave & 1;
  const int gm0 = blockIdx.y * 128;
  const int gnc = blockIdx.x * 128;   // concatenated col 0..6143
  const int seg = gnc >> 11;          // 0=q, 1=k, 2=v
  const bool split = (seg != 0);
  const int lrsub = lane >> 2;
  const int lcsub = lane & 3;

  f32x4 acc[4][4] = {};

  for (int kt = 0; kt < DM; kt += 32) {
    __syncthreads();
#pragma unroll
    for (int rg = wave; rg < 8; rg += 4) {
      const int lrow = rg * 16 + lrsub;
      const int c = lcsub ^ ((lrow >> 1) & 3);
      const size_t goffA = (size_t)(gm0 + lrow) * DM + kt + c * 8;
      const size_t goffB = (size_t)(gnc + lrow) * DM + kt + c * 8;
      stage16(Ahi + goffA, lAhi + rg * 512);
      stage16(Bhi + goffB, lBhi + rg * 512);
      if (split) {
        stage16(Alo + goffA, lAlo + rg * 512);
        stage16(Blo + goffB, lBlo + rg * 512);
      }
    }
    __syncthreads();

    bf16x8 ah[4], bh[4], al[4], bl[4];
#pragma unroll
    for (int i = 0; i < 4; ++i) {
      const int mrow = wr * 64 + i * 16 + (lane & 15);
      const int offa = mrow * 32 + (((lane >> 4) ^ ((mrow >> 1) & 3)) << 3);
      ah[i] = ldfrag(&lAhi[offa]);
      const int nrow = wc * 64 + i * 16 + (lane & 15);
      const int offb = nrow * 32 + (((lane >> 4) ^ ((nrow >> 1) & 3)) << 3);
      bh[i] = ldfrag(&lBhi[offb]);
      if (split) {
        al[i] = ldfrag(&lAlo[offa]);
        bl[i] = ldfrag(&lBlo[offb]);
      }
    }
#pragma unroll
    for (int i = 0; i < 4; ++i)
#pragma unroll
      for (int j = 0; j < 4; ++j) {
        acc[i][j] = MFMA16(ah[i], bh[j], acc[i][j]);
        if (split) {
          acc[i][j] = MFMA16(ah[i], bl[j], acc[i][j]);
          acc[i][j] = MFMA16(al[i], bh[j], acc[i][j]);
        }
      }
  }

  float* C = (seg == 0) ? q : (seg == 1) ? k : v;
  const int gn0 = gnc & 2047;
#pragma unroll
  for (int i = 0; i < 4; ++i) {
    const int row = gm0 + wr * 64 + i * 16 + ((lane >> 4) << 2);
#pragma unroll
    for (int j = 0; j < 4; ++j) {
      const int col = gn0 + wc * 64 + j * 16 + (lane & 15);
#pragma unroll
      for (int r = 0; r < 4; ++r)
        C[(size_t)(row + r) * DM + col] = acc[i][j][r];
    }
  }
}

// ---------------------------------------------------------------------------
// Output projection, split-K=2: grid (16,16,2); z covers K-half, writes
// partial C into Cpart + z*N*M. Plain bf16.
// ---------------------------------------------------------------------------
__global__ __launch_bounds__(256) void gemm_out_splitk_kernel(
    const unsigned short* __restrict__ Ahi, const unsigned short* __restrict__ Bt,
    float* __restrict__ Cpart) {
  __shared__ unsigned short lAhi[128 * 32];
  __shared__ unsigned short lBhi[128 * 32];

  const int t = threadIdx.x;
  const int lane = t & 63, wave = t >> 6;
  const int wr = wave >> 1, wc = wave & 1;
  const int gm0 = blockIdx.y * 128, gn0 = blockIdx.x * 128;
  const int z = blockIdx.z;
  const int k0 = z * (DM / 2);
  const int lrsub = lane >> 2;
  const int lcsub = lane & 3;

  f32x4 acc[4][4] = {};

  for (int kt = k0; kt < k0 + DM / 2; kt += 32) {
    __syncthreads();
#pragma unroll
    for (int rg = wave; rg < 8; rg += 4) {
      const int lrow = rg * 16 + lrsub;
      const int c = lcsub ^ ((lrow >> 1) & 3);
      stage16(Ahi + (size_t)(gm0 + lrow) * DM + kt + c * 8, lAhi + rg * 512);
      stage16(Bt + (size_t)(gn0 + lrow) * DM + kt + c * 8, lBhi + rg * 512);
    }
    __syncthreads();

    bf16x8 ah[4], bh[4];
#pragma unroll
    for (int i = 0; i < 4; ++i) {
      const int mrow = wr * 64 + i * 16 + (lane & 15);
      ah[i] = ldfrag(&lAhi[mrow * 32 + (((lane >> 4) ^ ((mrow >> 1) & 3)) << 3)]);
      const int nrow = wc * 64 + i * 16 + (lane & 15);
      bh[i] = ldfrag(&lBhi[nrow * 32 + (((lane >> 4) ^ ((nrow >> 1) & 3)) << 3)]);
    }
#pragma unroll
    for (int i = 0; i < 4; ++i)
#pragma unroll
      for (int j = 0; j < 4; ++j)
        acc[i][j] = MFMA16(ah[i], bh[j], acc[i][j]);
  }

  float* C = Cpart + (size_t)z * NROWS * DM;
#pragma unroll
  for (int i = 0; i < 4; ++i) {
    const int row = gm0 + wr * 64 + i * 16 + ((lane >> 4) << 2);
#pragma unroll
    for (int j = 0; j < 4; ++j) {
      const int col = gn0 + wc * 64 + j * 16 + (lane & 15);
#pragma unroll
      for (int r = 0; r < 4; ++r)
        C[(size_t)(row + r) * DM + col] = acc[i][j][r];
    }
  }
}

__global__ __launch_bounds__(256) void add2_f4_kernel(
    const float* __restrict__ a, const float* __restrict__ b,
    float* __restrict__ o, int n4) {
  const int i = blockIdx.x * 256 + threadIdx.x;
  if (i >= n4) return;
  const float4 x = ((const float4*)a)[i];
  const float4 y = ((const float4*)b)[i];
  ((float4*)o)[i] = make_float4(x.x + y.x, x.y + y.y, x.z + y.z, x.w + y.w);
}

// ---------------------------------------------------------------------------
// Wave reductions
// ---------------------------------------------------------------------------
__device__ __forceinline__ float wave_sum(float x) {
#pragma unroll
  for (int o = 32; o > 0; o >>= 1) x += __shfl_xor(x, o, 64);
  return x;
}

// ---------------------------------------------------------------------------
// RMSNorm in place (fp32), one block per row.  (k path)
// ---------------------------------------------------------------------------
__global__ __launch_bounds__(256) void rmsnorm_kernel(
    float* __restrict__ y, const float* __restrict__ w) {
  __shared__ float rbuf[4];
  const int row = blockIdx.x;
  float* p = y + (size_t)row * DM;
  const int t = threadIdx.x;
  const int wave = t >> 6, lane = t & 63;

  float ss = 0.f;
#pragma unroll
  for (int c = t; c < DM; c += 256) { float v = p[c]; ss += v * v; }
  ss = wave_sum(ss);
  if (lane == 0) rbuf[wave] = ss;
  __syncthreads();
  ss = rbuf[0] + rbuf[1] + rbuf[2] + rbuf[3];
  const float scale = rsqrtf(ss * (1.0f / DM) + EPS_RMS);
#pragma unroll
  for (int c = t; c < DM; c += 256) p[c] = p[c] * scale * w[c];
}

// ---------------------------------------------------------------------------
// RMSNorm -> bf16 hi/lo with extra post-scale (q path: folds 1/8)
// ---------------------------------------------------------------------------
__global__ __launch_bounds__(256) void rmsnorm_split_kernel(
    const float* __restrict__ y, const float* __restrict__ w,
    unsigned short* __restrict__ hi, unsigned short* __restrict__ lo,
    float post) {
  __shared__ float rbuf[4];
  const int row = blockIdx.x;
  const float* p = y + (size_t)row * DM;
  const int t = threadIdx.x;
  const int wave = t >> 6, lane = t & 63;

  const int c0 = t * 8;
  float4 a = *(const float4*)(p + c0);
  float4 b = *(const float4*)(p + c0 + 4);
  float v[8] = {a.x, a.y, a.z, a.w, b.x, b.y, b.z, b.w};
  float ss = 0.f;
#pragma unroll
  for (int j = 0; j < 8; ++j) ss += v[j] * v[j];
  ss = wave_sum(ss);
  if (lane == 0) rbuf[wave] = ss;
  __syncthreads();
  ss = rbuf[0] + rbuf[1] + rbuf[2] + rbuf[3];
  const float scale = rsqrtf(ss * (1.0f / DM) + EPS_RMS) * post;

  u16x8 hv, lv;
#pragma unroll
  for (int j = 0; j < 8; ++j) {
    const float val = v[j] * scale * w[c0 + j];
    const unsigned short hh = f2bf(val);
    hv[j] = hh; lv[j] = f2bf(val - bf2f(hh));
  }
  *(u16x8*)&hi[(size_t)row * DM + c0] = hv;
  *(u16x8*)&lo[(size_t)row * DM + c0] = lv;
}

// ---------------------------------------------------------------------------
// RotorQuant roundtrip. WRITE_BF: emit bf16 hi/lo; else fp32 in place.
// ---------------------------------------------------------------------------
__device__ __forceinline__ float qnearest(float v, const float* __restrict__ C) {
  float best = C[0];
  float bd = fabsf(v - C[0]);
#pragma unroll
  for (int i = 1; i < N_LEVELS; ++i) {
    float d = fabsf(v - C[i]);
    if (d < bd) { bd = d; best = C[i]; }
  }
  return best;
}

template <bool WRITE_BF>
__global__ __launch_bounds__(256) void quant_kernel(
    float* __restrict__ kv, const float* __restrict__ M,
    const float* __restrict__ Mt, const float* __restrict__ C,
    unsigned short* __restrict__ hi, unsigned short* __restrict__ lo) {
  const int vec = blockIdx.x * blockDim.x + threadIdx.x;
  if (vec >= NVEC) return;
  float* p = kv + (size_t)vec * DIM_HEAD;

  float h[66];
  float ss = 0.f;
#pragma unroll
  for (int d = 0; d < DIM_HEAD; ++d) { h[d] = p[d]; ss += h[d] * h[d]; }
  float norm = fmaxf(sqrtf(ss), EPS_NORM);
  const float inv = 1.0f / norm;
#pragma unroll
  for (int d = 0; d < DIM_HEAD; ++d) h[d] *= inv;
  h[64] = 0.f; h[65] = 0.f;

#pragma unroll
  for (int g = 0; g < N_GROUPS; ++g) {
    const float* Mg  = M  + g * 9;
    const float* Mtg = Mt + g * 9;
    const float a0 = h[3 * g + 0], a1 = h[3 * g + 1], a2 = h[3 * g + 2];
    const float r0 = a0 * Mg[0] + a1 * Mg[3] + a2 * Mg[6];
    const float r1 = a0 * Mg[1] + a1 * Mg[4] + a2 * Mg[7];
    const float r2 = a0 * Mg[2] + a1 * Mg[5] + a2 * Mg[8];
    const float d0 = qnearest(r0, C);
    const float d1 = qnearest(r1, C);
    const float d2 = qnearest(r2, C);
    h[3 * g + 0] = d0 * Mtg[0] + d1 * Mtg[3] + d2 * Mtg[6];
    h[3 * g + 1] = d0 * Mtg[1] + d1 * Mtg[4] + d2 * Mtg[7];
    h[3 * g + 2] = d0 * Mtg[2] + d1 * Mtg[5] + d2 * Mtg[8];
  }
  if (WRITE_BF) {
#pragma unroll
    for (int g8 = 0; g8 < 8; ++g8) {
      u16x8 hv, lv;
#pragma unroll
      for (int j = 0; j < 8; ++j) {
        const float val = h[g8 * 8 + j] * norm;
        const unsigned short hh = f2bf(val);
        hv[j] = hh; lv[j] = f2bf(val - bf2f(hh));
      }
      *(u16x8*)&hi[(size_t)vec * DIM_HEAD + g8 * 8] = hv;
      *(u16x8*)&lo[(size_t)vec * DIM_HEAD + g8 * 8] = lv;
    }
  } else {
#pragma unroll
    for (int d = 0; d < DIM_HEAD; ++d) p[d] = h[d] * norm;
  }
}

// ---------------------------------------------------------------------------
// Per-head V transpose + split: v[b][s][h*64+d] fp32 -> vt[(bh*64+d)][s] hi/lo
// ---------------------------------------------------------------------------
__global__ __launch_bounds__(256) void vt_split_kernel(
    const float* __restrict__ v, unsigned short* __restrict__ hi,
    unsigned short* __restrict__ lo) {
  __shared__ float T[64][65];
  const int s0 = blockIdx.x * 64;
  const int bh = blockIdx.y;
  const int b = bh >> 5, h = bh & 31;
  const int t = threadIdx.x;
  {
    const int sr = t >> 2, dseg = (t & 3) * 16;
    const float* src = v + ((size_t)(b * SEQ + s0 + sr) * DM + h * 64 + dseg);
#pragma unroll
    for (int j = 0; j < 16; j += 4) {
      float4 a = *(const float4*)(src + j);
      T[sr][dseg + j] = a.x; T[sr][dseg + j + 1] = a.y;
      T[sr][dseg + j + 2] = a.z; T[sr][dseg + j + 3] = a.w;
    }
  }
  __syncthreads();
  const int d = t >> 2, sseg = (t & 3) * 16;
  u16x8 h0, h1, l0, l1;
#pragma unroll
  for (int j = 0; j < 8; ++j) {
    const float val = T[sseg + j][d];
    const unsigned short hh = f2bf(val);
    h0[j] = hh; l0[j] = f2bf(val - bf2f(hh));
  }
#pragma unroll
  for (int j = 0; j < 8; ++j) {
    const float val = T[sseg + 8 + j][d];
    const unsigned short hh = f2bf(val);
    h1[j] = hh; l1[j] = f2bf(val - bf2f(hh));
  }
  const size_t o = (size_t)(bh * 64 + d) * SEQ + s0 + sseg;
  *(u16x8*)&hi[o] = h0; *(u16x8*)&hi[o + 8] = h1;
  *(u16x8*)&lo[o] = l0; *(u16x8*)&lo[o + 8] = l1;
}

// ---------------------------------------------------------------------------
// MFMA flash attention, split-bf16 (unchanged from round 4).
// ---------------------------------------------------------------------------
__global__ __launch_bounds__(256) void attn_mfma_kernel(
    const unsigned short* __restrict__ qhi, const unsigned short* __restrict__ qlo,
    const unsigned short* __restrict__ khi, const unsigned short* __restrict__ klo,
    const unsigned short* __restrict__ vthi, const unsigned short* __restrict__ vtlo,
    unsigned short* __restrict__ ohi) {
  __shared__ unsigned short Ks_h[4096], Ks_l[4096];
  __shared__ unsigned short Vt_h[4096], Vt_l[4096];
  __shared__ unsigned short Ps_h[4096], Ps_l[4096];
  __shared__ float alpha_s[4][16];
  __shared__ float l_s[4][16];

  const int qt = blockIdx.x;
  const int bh = blockIdx.y;
  const int h = bh & 31, b = bh >> 5;
  const int q0 = qt * 64;
  const int t = threadIdx.x, lane = t & 63, w = t >> 6;
  const int quad = lane >> 4, l15 = lane & 15;
  const int srow = lane >> 3, schunk = lane & 7;

  auto stage = [&](const unsigned short* g, int stride, unsigned short* arr) {
#pragma unroll
    for (int it = 0; it < 2; ++it) {
      const int r = w * 16 + it * 8 + srow;
      const int c = schunk ^ (r & 7);
      stage16(g + (size_t)r * stride + c * 8, arr + (w * 16 + it * 8) * 64);
    }
  };

  stage(qhi + ((size_t)(b * SEQ + q0) * DM + h * 64), DM, Ps_h);
  stage(qlo + ((size_t)(b * SEQ + q0) * DM + h * 64), DM, Ps_l);
  __syncthreads();
  bf16x8 qh[2], ql[2];
#pragma unroll
  for (int ks = 0; ks < 2; ++ks) {
    const int row = w * 16 + l15;
    const int off = row * 64 + (((quad + 4 * ks) ^ (row & 7)) << 3);
    qh[ks] = ldfrag(&Ps_h[off]);
    ql[ks] = ldfrag(&Ps_l[off]);
  }

  f32x4 acc[4] = {};
  float m_prev[4] = {-INFINITY, -INFINITY, -INFINITY, -INFINITY};
  float lsum[4] = {0.f, 0.f, 0.f, 0.f};

  const unsigned short* gkh = khi + ((size_t)(b * SEQ) * DM + h * 64);
  const unsigned short* gkl = klo + ((size_t)(b * SEQ) * DM + h * 64);
  const unsigned short* gvh = vthi + (size_t)(bh * 64) * SEQ;
  const unsigned short* gvl = vtlo + (size_t)(bh * 64) * SEQ;

  for (int kt = 0; kt < SEQ; kt += 64) {
    __syncthreads();
    stage(gkh + (size_t)kt * DM, DM, Ks_h);
    stage(gkl + (size_t)kt * DM, DM, Ks_l);
    stage(gvh + kt, SEQ, Vt_h);
    stage(gvl + kt, SEQ, Vt_l);
    __syncthreads();

    f32x4 s[4] = {};
#pragma unroll
    for (int nt = 0; nt < 4; ++nt) {
#pragma unroll
      for (int ks = 0; ks < 2; ++ks) {
        const int row = nt * 16 + l15;
        const int off = row * 64 + (((quad + 4 * ks) ^ (row & 7)) << 3);
        const bf16x8 kh = ldfrag(&Ks_h[off]);
        const bf16x8 kl = ldfrag(&Ks_l[off]);
        s[nt] = MFMA16(qh[ks], kh, s[nt]);
        s[nt] = MFMA16(qh[ks], kl, s[nt]);
        s[nt] = MFMA16(ql[ks], kh, s[nt]);
      }
    }

    float asave[4];
#pragma unroll
    for (int r = 0; r < 4; ++r) {
      float mx = fmaxf(fmaxf(s[0][r], s[1][r]), fmaxf(s[2][r], s[3][r]));
#pragma unroll
      for (int off = 1; off < 16; off <<= 1) mx = fmaxf(mx, __shfl_xor(mx, off, 64));
      const float mn = fmaxf(m_prev[r], mx);
      const float al = __expf(m_prev[r] - mn);
      float rs = 0.f;
#pragma unroll
      for (int nt = 0; nt < 4; ++nt) {
        const float e = __expf(s[nt][r] - mn);
        s[nt][r] = e; rs += e;
      }
#pragma unroll
      for (int off = 1; off < 16; off <<= 1) rs += __shfl_xor(rs, off, 64);
      lsum[r] = lsum[r] * al + rs;
      m_prev[r] = mn;
      asave[r] = al;
      const int prow = w * 16 + quad * 4 + r;
#pragma unroll
      for (int nt = 0; nt < 4; ++nt) {
        const int kk = nt * 16 + l15;
        const int off2 = prow * 64 + (((kk >> 3) ^ (prow & 7)) << 3) + (kk & 7);
        const unsigned short hh = f2bf(s[nt][r]);
        Ps_h[off2] = hh;
        Ps_l[off2] = f2bf(s[nt][r] - bf2f(hh));
      }
    }

    if (l15 == 0) {
#pragma unroll
      for (int r = 0; r < 4; ++r) alpha_s[w][quad * 4 + r] = asave[r];
    }
    const float alph = alpha_s[w][l15];
#pragma unroll
    for (int mt = 0; mt < 4; ++mt) acc[mt] *= alph;

#pragma unroll
    for (int mt = 0; mt < 4; ++mt) {
#pragma unroll
      for (int ks = 0; ks < 2; ++ks) {
        const int drow = mt * 16 + l15;
        const int offv = drow * 64 + (((quad + 4 * ks) ^ (drow & 7)) << 3);
        const bf16x8 vh = ldfrag(&Vt_h[offv]);
        const bf16x8 vl = ldfrag(&Vt_l[offv]);
        const int prow = w * 16 + l15;
        const int offp = prow * 64 + (((quad + 4 * ks) ^ (prow & 7)) << 3);
        const bf16x8 ph = ldfrag(&Ps_h[offp]);
        const bf16x8 pl = ldfrag(&Ps_l[offp]);
        acc[mt] = MFMA16(vh, ph, acc[mt]);
        acc[mt] = MFMA16(vh, pl, acc[mt]);
        acc[mt] = MFMA16(vl, ph, acc[mt]);
      }
    }
  }

  if (l15 == 0) {
#pragma unroll
    for (int r = 0; r < 4; ++r) l_s[w][quad * 4 + r] = lsum[r];
  }
  const float inv = 1.0f / l_s[w][l15];
  const size_t obase = (size_t)(b * SEQ + q0 + w * 16 + l15) * DM + h * 64;
#pragma unroll
  for (int mt = 0; mt < 4; ++mt) {
    u16x4 ov;
#pragma unroll
    for (int r = 0; r < 4; ++r) ov[r] = f2bf(acc[mt][r] * inv);
    *(u16x4*)&ohi[obase + mt * 16 + quad * 4] = ov;
  }
}

// ---------------------------------------------------------------------------
// Launch
// ---------------------------------------------------------------------------
extern "C" void kernel_launch(void* const* d_in, const int* in_sizes, int n_in,
                              void* d_out, int out_size, void* d_ws, size_t ws_size,
                              hipStream_t stream) {
  const float* x    = (const float*)d_in[0];
  const float* Wq   = (const float*)d_in[1];
  const float* Wk   = (const float*)d_in[2];
  const float* Wv   = (const float*)d_in[3];
  const float* Wo   = (const float*)d_in[4];
  const float* qn_w = (const float*)d_in[5];
  const float* kn_w = (const float*)d_in[6];
  const float* Mk   = (const float*)d_in[7];
  const float* Mtk  = (const float*)d_in[8];
  const float* Ck   = (const float*)d_in[9];
  const float* Mv   = (const float*)d_in[10];
  const float* Mtv  = (const float*)d_in[11];
  const float* Cv   = (const float*)d_in[12];
  float* out = (float*)d_out;

  const size_t MBb = 1024ull * 1024ull;
  const size_t SEG = (size_t)DM * DM;  // 4 Mi elements
  char* w = (char*)d_ws;
  float* qb = (float*)(w + 0 * MBb);        // 16 MB each
  float* kb = (float*)(w + 16 * MBb);
  float* vb = (float*)(w + 32 * MBb);
  unsigned short* xhi     = (unsigned short*)(w + 48 * MBb);  // 8 MB each
  unsigned short* xlo     = (unsigned short*)(w + 56 * MBb);
  unsigned short* wcat_hi = (unsigned short*)(w + 64 * MBb);  // 24 MB [6144][2048]
  unsigned short* wcat_lo = (unsigned short*)(w + 88 * MBb);  // 24 MB
  unsigned short* wot     = (unsigned short*)(w + 112 * MBb); // 8 MB
  // Reuse (stream-ordered death):
  unsigned short* q_hi  = wcat_hi;            // seg0 dead after qkv gemm
  unsigned short* k_hi  = wcat_hi + SEG;      // seg1 dead after qkv gemm
  unsigned short* k_lo  = wcat_hi + 2 * SEG;  // seg2 dead after qkv gemm
  unsigned short* q_lo  = wcat_lo;            // seg0 never used by gemm
  unsigned short* vt_hi = wcat_lo + SEG;      // seg1 dead after qkv gemm
  unsigned short* vt_lo = wcat_lo + 2 * SEG;  // seg2 dead after qkv gemm
  unsigned short* o_hi  = xhi;                // x dead after qkv gemm
  float* opart = (float*)(w + 0 * MBb);       // 32 MB; qb/kb dead by out-GEMM

  const int n8 = (NROWS * DM) / 8;

  split_convert_kernel<<<n8 / 256, 256, 0, stream>>>(x, xhi, xlo, n8);
  transpose_split_batch_kernel<<<dim3(DM / 64, DM / 64, 4), 256, 0, stream>>>(
      Wq, Wk, Wv, Wo,
      wcat_hi, wcat_hi + SEG, wcat_lo + SEG, wcat_hi + 2 * SEG, wcat_lo + 2 * SEG, wot);

  qkv_gemm_kernel<<<dim3(3 * DM / 128, NROWS / 128), 256, 0, stream>>>(
      xhi, xlo, wcat_hi, wcat_lo, qb, kb, vb);

  rmsnorm_kernel<<<NROWS, 256, 0, stream>>>(kb, kn_w);
  rmsnorm_split_kernel<<<NROWS, 256, 0, stream>>>(qb, qn_w, q_hi, q_lo, 0.125f);

  quant_kernel<true ><<<NVEC / 256, 256, 0, stream>>>(kb, Mk, Mtk, Ck, k_hi, k_lo);
  quant_kernel<false><<<NVEC / 256, 256, 0, stream>>>(vb, Mv, Mtv, Cv, nullptr, nullptr);
  vt_split_kernel<<<dim3(SEQ / 64, BATCH * HEADS), 256, 0, stream>>>(vb, vt_hi, vt_lo);

  attn_mfma_kernel<<<dim3(SEQ / 64, BATCH * HEADS), 256, 0, stream>>>(
      q_hi, q_lo, k_hi, k_lo, vt_hi, vt_lo, o_hi);

  gemm_out_splitk_kernel<<<dim3(DM / 128, NROWS / 128, 2), 256, 0, stream>>>(
      o_hi, wot, opart);
  add2_f4_kernel<<<(NROWS * DM / 4 + 255) / 256, 256, 0, stream>>>(
      opart, opart + (size_t)NROWS * DM, out, NROWS * DM / 4);
}